// Round 1
// baseline (3231.270 us; speedup 1.0000x reference)
//
#include <hip/hip_runtime.h>
#include <math.h>

#define BATCH   2
#define SLEN    2048
#define DMODEL  1024
#define NHEAD   16
#define DHEAD   64
#define DOUT    2048
#define MROWS   (BATCH * SLEN)   // 4096

// ================= GEMM: C[M,N] = A[M,K] @ W[K,N] + bias[N] =================
// 64x64 tile, Ktile=16, 256 threads, 4x4 micro-tile per thread.
__global__ __launch_bounds__(256) void gemm_bias_k(
    const float* __restrict__ A, const float* __restrict__ W,
    const float* __restrict__ bias, float* __restrict__ C,
    int M, int K, int N) {
  __shared__ __align__(16) float As[16][68];   // [k][m], +4 pad keeps 16B align, 2-way max conflict
  __shared__ __align__(16) float Bs[16][68];   // [k][n]
  const int t = threadIdx.x;
  const int tx = t & 15, ty = t >> 4;
  const int row0 = blockIdx.y * 64, col0 = blockIdx.x * 64;
  const int am = t >> 2, ak = (t & 3) * 4;   // A tile: 64 rows x 16 k as float4 over k
  const int wk = t >> 4, wn = (t & 15) * 4;  // W tile: 16 k x 64 n as float4 over n

  float acc[4][4] = {{0.f, 0.f, 0.f, 0.f}, {0.f, 0.f, 0.f, 0.f},
                     {0.f, 0.f, 0.f, 0.f}, {0.f, 0.f, 0.f, 0.f}};

  for (int kt = 0; kt < K; kt += 16) {
    const float4 a4 = *(const float4*)(A + (size_t)(row0 + am) * K + (kt + ak));
    const float4 w4 = *(const float4*)(W + (size_t)(kt + wk) * N + (col0 + wn));
    As[ak + 0][am] = a4.x;
    As[ak + 1][am] = a4.y;
    As[ak + 2][am] = a4.z;
    As[ak + 3][am] = a4.w;
    *(float4*)&Bs[wk][wn] = w4;
    __syncthreads();
#pragma unroll
    for (int kk = 0; kk < 16; kk++) {
      const float4 a = *(const float4*)&As[kk][ty * 4];
      const float4 w = *(const float4*)&Bs[kk][tx * 4];
      const float av[4] = {a.x, a.y, a.z, a.w};
      const float wv[4] = {w.x, w.y, w.z, w.w};
#pragma unroll
      for (int i = 0; i < 4; i++)
#pragma unroll
        for (int j = 0; j < 4; j++)
          acc[i][j] = fmaf(av[i], wv[j], acc[i][j]);
    }
    __syncthreads();
  }
  const float4 bi = *(const float4*)(bias + col0 + tx * 4);
  const float bv[4] = {bi.x, bi.y, bi.z, bi.w};
#pragma unroll
  for (int i = 0; i < 4; i++) {
    float4 o;
    o.x = acc[i][0] + bv[0];
    o.y = acc[i][1] + bv[1];
    o.z = acc[i][2] + bv[2];
    o.w = acc[i][3] + bv[3];
    *(float4*)(C + (size_t)(row0 + ty * 4 + i) * N + col0 + tx * 4) = o;
  }
}

// ============ Flash attention per (b, h, 64-row q tile); 1 wave, lane = q row.
// Writes attended[B,S,D] (heads interleaved at h*64) and per-row softmax m,l.
__global__ __launch_bounds__(64) void flash_attn_k(
    const float* __restrict__ Qp, const float* __restrict__ Kp,
    const float* __restrict__ Vp, const int* __restrict__ mask,
    float* __restrict__ att, float* __restrict__ mbuf, float* __restrict__ lbuf) {
  const int tid = threadIdx.x;
  const int q0 = blockIdx.x * 64;
  const int h  = blockIdx.y;
  const int b  = blockIdx.z;
  __shared__ __align__(16) float Ks[64 * 64];
  __shared__ __align__(16) float Vs[64 * 64];

  float4 qf[16];
  const float* qrow = Qp + ((size_t)(b * SLEN + q0 + tid)) * DMODEL + h * DHEAD;
#pragma unroll
  for (int i = 0; i < 16; i++) qf[i] = ((const float4*)qrow)[i];

  float4 o[16];
#pragma unroll
  for (int i = 0; i < 16; i++) o[i] = make_float4(0.f, 0.f, 0.f, 0.f);
  float m = -INFINITY, l = 0.f;

  for (int k0 = 0; k0 < SLEN; k0 += 64) {
    __syncthreads();
#pragma unroll 4
    for (int i = 0; i < 16; i++) {
      const int idx = tid + i * 64;  // j = idx>>4, d4 = idx&15 -> coalesced 256B rows
      const size_t base =
          ((size_t)(b * SLEN + k0 + (idx >> 4))) * DMODEL + h * DHEAD + (idx & 15) * 4;
      ((float4*)Ks)[idx] = *(const float4*)(Kp + base);
      ((float4*)Vs)[idx] = *(const float4*)(Vp + base);
    }
    __syncthreads();
    for (int j = 0; j < 64; j++) {
      if (mask[b * SLEN + k0 + j] == 0) continue;  // wave-uniform branch
      const float4* kr = (const float4*)(Ks + j * 64);  // broadcast reads, conflict-free
      float s = 0.f;
#pragma unroll
      for (int i = 0; i < 16; i++) {
        const float4 kv = kr[i];
        s = fmaf(qf[i].x, kv.x, s);
        s = fmaf(qf[i].y, kv.y, s);
        s = fmaf(qf[i].z, kv.z, s);
        s = fmaf(qf[i].w, kv.w, s);
      }
      s *= 0.125f;  // 1/sqrt(64)
      const float mnew  = fmaxf(m, s);
      const float alpha = __expf(m - mnew);   // m=-inf first iter -> exp(-inf)=0
      const float p     = __expf(s - mnew);
      l = l * alpha + p;
      const float4* vr = (const float4*)(Vs + j * 64);
#pragma unroll
      for (int i = 0; i < 16; i++) {
        const float4 vv = vr[i];
        o[i].x = fmaf(o[i].x, alpha, p * vv.x);
        o[i].y = fmaf(o[i].y, alpha, p * vv.y);
        o[i].z = fmaf(o[i].z, alpha, p * vv.z);
        o[i].w = fmaf(o[i].w, alpha, p * vv.w);
      }
      m = mnew;
    }
  }
  const float il = 1.f / l;
  float* orow = att + ((size_t)(b * SLEN + q0 + tid)) * DMODEL + h * DHEAD;
#pragma unroll
  for (int i = 0; i < 16; i++) {
    float4 ov;
    ov.x = o[i].x * il; ov.y = o[i].y * il; ov.z = o[i].z * il; ov.w = o[i].w * il;
    ((float4*)orow)[i] = ov;
  }
  const int qi = (b * NHEAD + h) * SLEN + q0 + tid;
  mbuf[qi] = m;
  lbuf[qi] = l;
}

// ======= attn_avg[b,q,k] = (1/H) sum_h exp(s_h(q,k) - m[b,h,q]) / l[b,h,q] ====
// Block = (64 k cols) x (64 q rows); 1 wave, lane = q row; loop heads inside.
__global__ __launch_bounds__(64) void attn_avg_k(
    const float* __restrict__ Qp, const float* __restrict__ Kp,
    const float* __restrict__ mbuf, const float* __restrict__ lbuf,
    const int* __restrict__ mask, float* __restrict__ aout) {
  const int tid = threadIdx.x;
  const int k0 = blockIdx.x * 64;
  const int q0 = blockIdx.y * 64;
  const int b  = blockIdx.z;
  __shared__ __align__(16) float Ks[64 * 64];
  __shared__ float accL[64 * 65];  // [q-lane][k], stride 65 -> conflict-free

  for (int j = 0; j < 64; j++) accL[tid * 65 + j] = 0.f;

  for (int h = 0; h < NHEAD; h++) {
    __syncthreads();
#pragma unroll 4
    for (int i = 0; i < 16; i++) {
      const int idx = tid + i * 64;
      const size_t base =
          ((size_t)(b * SLEN + k0 + (idx >> 4))) * DMODEL + h * DHEAD + (idx & 15) * 4;
      ((float4*)Ks)[idx] = *(const float4*)(Kp + base);
    }
    __syncthreads();
    float4 qf[16];
    const float* qrow = Qp + ((size_t)(b * SLEN + q0 + tid)) * DMODEL + h * DHEAD;
#pragma unroll
    for (int i = 0; i < 16; i++) qf[i] = ((const float4*)qrow)[i];
    const int qi = (b * NHEAD + h) * SLEN + q0 + tid;
    const float mm = mbuf[qi];
    const float il = 1.f / lbuf[qi];
    for (int j = 0; j < 64; j++) {
      if (mask[b * SLEN + k0 + j] == 0) continue;  // masked -> prob 0, acc unchanged
      const float4* kr = (const float4*)(Ks + j * 64);
      float s = 0.f;
#pragma unroll
      for (int i = 0; i < 16; i++) {
        const float4 kv = kr[i];
        s = fmaf(qf[i].x, kv.x, s);
        s = fmaf(qf[i].y, kv.y, s);
        s = fmaf(qf[i].z, kv.z, s);
        s = fmaf(qf[i].w, kv.w, s);
      }
      s *= 0.125f;
      accL[tid * 65 + j] += __expf(s - mm) * il;
    }
  }
  const float inv_h = 1.f / NHEAD;
  float* arow = aout + ((size_t)(b * SLEN + q0 + tid)) * SLEN + k0;
#pragma unroll
  for (int j4 = 0; j4 < 16; j4++) {
    float4 ov;
    ov.x = accL[tid * 65 + j4 * 4 + 0] * inv_h;
    ov.y = accL[tid * 65 + j4 * 4 + 1] * inv_h;
    ov.z = accL[tid * 65 + j4 * 4 + 2] * inv_h;
    ov.w = accL[tid * 65 + j4 * 4 + 3] * inv_h;
    ((float4*)arow)[j4] = ov;
  }
}

extern "C" void kernel_launch(void* const* d_in, const int* in_sizes, int n_in,
                              void* d_out, int out_size, void* d_ws, size_t ws_size,
                              hipStream_t stream) {
  const float* q   = (const float*)d_in[0];
  const float* k   = (const float*)d_in[1];
  const float* v   = (const float*)d_in[2];
  const float* Wq  = (const float*)d_in[3];
  const float* bq  = (const float*)d_in[4];
  const float* Wk  = (const float*)d_in[5];
  const float* bk  = (const float*)d_in[6];
  const float* Wv  = (const float*)d_in[7];
  const float* bv  = (const float*)d_in[8];
  const float* Wfc = (const float*)d_in[9];
  const float* bfc = (const float*)d_in[10];
  const int* mask  = (const int*)d_in[11];

  float* out      = (float*)d_out;                    // [B,S,2D] = 8388608 f32
  float* attn_avg = out + (size_t)MROWS * DOUT;       // [B,S,S]  = 8388608 f32

  // Workspace layout (f32): Qp,Kp,Vp,attended each MROWS*DMODEL; m,l each B*H*S.
  float* ws   = (float*)d_ws;
  float* Qp   = ws;
  float* Kp   = Qp + (size_t)MROWS * DMODEL;
  float* Vp   = Kp + (size_t)MROWS * DMODEL;
  float* att  = Vp + (size_t)MROWS * DMODEL;
  float* mbuf = att + (size_t)MROWS * DMODEL;
  float* lbuf = mbuf + (size_t)BATCH * NHEAD * SLEN;

  // 1) projections
  gemm_bias_k<<<dim3(DMODEL / 64, MROWS / 64), dim3(256), 0, stream>>>(
      q, Wq, bq, Qp, MROWS, DMODEL, DMODEL);
  gemm_bias_k<<<dim3(DMODEL / 64, MROWS / 64), dim3(256), 0, stream>>>(
      k, Wk, bk, Kp, MROWS, DMODEL, DMODEL);
  gemm_bias_k<<<dim3(DMODEL / 64, MROWS / 64), dim3(256), 0, stream>>>(
      v, Wv, bv, Vp, MROWS, 2 * DMODEL, DMODEL);
  // 2) flash attention -> attended + (m,l)
  flash_attn_k<<<dim3(SLEN / 64, NHEAD, BATCH), dim3(64), 0, stream>>>(
      Qp, Kp, Vp, mask, att, mbuf, lbuf);
  // 3) head-averaged attention map (recompute scores with saved m,l)
  attn_avg_k<<<dim3(SLEN / 64, SLEN / 64, BATCH), dim3(64), 0, stream>>>(
      Qp, Kp, mbuf, lbuf, mask, attn_avg);
  // 4) output FC
  gemm_bias_k<<<dim3(DOUT / 64, MROWS / 64), dim3(256), 0, stream>>>(
      att, Wfc, bfc, out, MROWS, DMODEL, DOUT);
}

// Round 2
// 2734.244 us; speedup vs baseline: 1.1818x; 1.1818x over previous
//
#include <hip/hip_runtime.h>
#include <math.h>

#define BATCH   2
#define SLEN    2048
#define DMODEL  1024
#define NHEAD   16
#define DHEAD   64
#define DOUT    2048
#define MROWS   (BATCH * SLEN)   // 4096
#define NSPLIT  4
#define KSPAN   (SLEN / NSPLIT)  // 512

// bf16 pack/unpack (RNE), dependency-free
static __device__ __forceinline__ unsigned short f2bf(float f) {
  unsigned u = __float_as_uint(f);
  u += 0x7fff + ((u >> 16) & 1);
  return (unsigned short)(u >> 16);
}
static __device__ __forceinline__ float bf2f(unsigned short s) {
  return __uint_as_float(((unsigned)s) << 16);
}

// ================= GEMM: C[M,N] = A[M,K] @ W[K,N] + bias[N] =================
__global__ __launch_bounds__(256) void gemm_bias_k(
    const float* __restrict__ A, const float* __restrict__ W,
    const float* __restrict__ bias, float* __restrict__ C,
    int M, int K, int N) {
  __shared__ __align__(16) float As[16][68];
  __shared__ __align__(16) float Bs[16][68];
  const int t = threadIdx.x;
  const int tx = t & 15, ty = t >> 4;
  const int row0 = blockIdx.y * 64, col0 = blockIdx.x * 64;
  const int am = t >> 2, ak = (t & 3) * 4;
  const int wk = t >> 4, wn = (t & 15) * 4;

  float acc[4][4] = {{0.f, 0.f, 0.f, 0.f}, {0.f, 0.f, 0.f, 0.f},
                     {0.f, 0.f, 0.f, 0.f}, {0.f, 0.f, 0.f, 0.f}};

  for (int kt = 0; kt < K; kt += 16) {
    const float4 a4 = *(const float4*)(A + (size_t)(row0 + am) * K + (kt + ak));
    const float4 w4 = *(const float4*)(W + (size_t)(kt + wk) * N + (col0 + wn));
    As[ak + 0][am] = a4.x;
    As[ak + 1][am] = a4.y;
    As[ak + 2][am] = a4.z;
    As[ak + 3][am] = a4.w;
    *(float4*)&Bs[wk][wn] = w4;
    __syncthreads();
#pragma unroll
    for (int kk = 0; kk < 16; kk++) {
      const float4 a = *(const float4*)&As[kk][ty * 4];
      const float4 w = *(const float4*)&Bs[kk][tx * 4];
      const float av[4] = {a.x, a.y, a.z, a.w};
      const float wv[4] = {w.x, w.y, w.z, w.w};
#pragma unroll
      for (int i = 0; i < 4; i++)
#pragma unroll
        for (int j = 0; j < 4; j++)
          acc[i][j] = fmaf(av[i], wv[j], acc[i][j]);
    }
    __syncthreads();
  }
  const float4 bi = *(const float4*)(bias + col0 + tx * 4);
  const float bv[4] = {bi.x, bi.y, bi.z, bi.w};
#pragma unroll
  for (int i = 0; i < 4; i++) {
    float4 o;
    o.x = acc[i][0] + bv[0];
    o.y = acc[i][1] + bv[1];
    o.z = acc[i][2] + bv[2];
    o.w = acc[i][3] + bv[3];
    *(float4*)(C + (size_t)(row0 + ty * 4 + i) * N + col0 + tx * 4) = o;
  }
}

// ====== Flash attention partial: (b, h, split, q-tile64), 1 wave, lane=q row.
// K/V rows read directly from global (wave-uniform -> broadcast/scalar loads).
// Writes per-split normalized o (bf16) and (m,l) partial stats.
__global__ __launch_bounds__(64) void flash_part_k(
    const float* __restrict__ Qp, const float* __restrict__ Kp,
    const float* __restrict__ Vp, const int* __restrict__ mask,
    unsigned short* __restrict__ opart, float* __restrict__ mpart,
    float* __restrict__ lpart) {
  const int tid   = threadIdx.x;
  const int h     = blockIdx.x >> 2;   // gridX = H*NSPLIT: same (b,h,split) blocks
  const int split = blockIdx.x & 3;    // share same x -> linear ids stride 64 -> same XCD
  const int q0    = blockIdx.y * 64;
  const int b     = blockIdx.z;

  const float* qrow = Qp + ((size_t)(b * SLEN + q0 + tid)) * DMODEL + h * DHEAD;
  float4 qf[16];
#pragma unroll
  for (int i = 0; i < 16; i++) qf[i] = ((const float4*)qrow)[i];

  float4 o[16];
#pragma unroll
  for (int i = 0; i < 16; i++) o[i] = make_float4(0.f, 0.f, 0.f, 0.f);
  float m = -INFINITY, l = 0.f;

  const int kbeg = split * KSPAN, kend = kbeg + KSPAN;
  for (int j = kbeg; j < kend; j++) {
    if (mask[b * SLEN + j] == 0) continue;  // wave-uniform
    const float4* kr = (const float4*)(Kp + ((size_t)(b * SLEN + j)) * DMODEL + h * DHEAD);
    const float4* vr = (const float4*)(Vp + ((size_t)(b * SLEN + j)) * DMODEL + h * DHEAD);
    float s = 0.f;
#pragma unroll
    for (int i = 0; i < 16; i++) {
      const float4 kv = kr[i];
      s = fmaf(qf[i].x, kv.x, s);
      s = fmaf(qf[i].y, kv.y, s);
      s = fmaf(qf[i].z, kv.z, s);
      s = fmaf(qf[i].w, kv.w, s);
    }
    s *= 0.125f;  // 1/sqrt(64)
    const float mnew  = fmaxf(m, s);
    const float alpha = __expf(m - mnew);
    const float p     = __expf(s - mnew);
    l = l * alpha + p;
#pragma unroll
    for (int i = 0; i < 16; i++) {
      const float4 vv = vr[i];
      o[i].x = fmaf(o[i].x, alpha, p * vv.x);
      o[i].y = fmaf(o[i].y, alpha, p * vv.y);
      o[i].z = fmaf(o[i].z, alpha, p * vv.z);
      o[i].w = fmaf(o[i].w, alpha, p * vv.w);
    }
    m = mnew;
  }

  const float il = (l > 0.f) ? 1.f / l : 0.f;
  const size_t pi = ((size_t)((b * NHEAD + h) * NSPLIT + split)) * SLEN + q0 + tid;
  unsigned short* orow = opart + pi * DHEAD;
#pragma unroll
  for (int i = 0; i < 16; i++) {
    ushort4 u;
    u.x = f2bf(o[i].x * il);
    u.y = f2bf(o[i].y * il);
    u.z = f2bf(o[i].z * il);
    u.w = f2bf(o[i].w * il);
    ((ushort4*)orow)[i] = u;
  }
  mpart[pi] = m;
  lpart[pi] = l;
}

// ====== Combine NSPLIT partial softmax states -> att row + final (m,l) =======
// One block (64 lanes = dh) per (b,h,q).
__global__ __launch_bounds__(64) void flash_combine_k(
    const unsigned short* __restrict__ opart, const float* __restrict__ mpart,
    const float* __restrict__ lpart, float* __restrict__ att,
    float* __restrict__ mbuf, float* __restrict__ lbuf) {
  const int d = threadIdx.x;
  const int q = blockIdx.x;
  const int h = blockIdx.y;
  const int b = blockIdx.z;
  const size_t base = ((size_t)(b * NHEAD + h)) * NSPLIT * SLEN + q;

  float ms[NSPLIT], ls[NSPLIT];
  float mstar = -INFINITY;
#pragma unroll
  for (int s = 0; s < NSPLIT; s++) {
    ms[s] = mpart[base + (size_t)s * SLEN];
    ls[s] = lpart[base + (size_t)s * SLEN];
    mstar = fmaxf(mstar, ms[s]);
  }
  float Wt = 0.f, acc = 0.f;
#pragma unroll
  for (int s = 0; s < NSPLIT; s++) {
    const float w = (ls[s] > 0.f) ? ls[s] * __expf(ms[s] - mstar) : 0.f;
    Wt += w;
    const float ov = bf2f(opart[(base + (size_t)s * SLEN) * DHEAD + d]);
    acc = fmaf(ov, w, acc);
  }
  const float invW = (Wt > 0.f) ? 1.f / Wt : 0.f;
  att[((size_t)(b * SLEN + q)) * DMODEL + h * DHEAD + d] = acc * invW;
  if (d == 0) {
    const size_t qi = ((size_t)(b * NHEAD + h)) * SLEN + q;
    mbuf[qi] = mstar;
    lbuf[qi] = Wt;
  }
}

// ======= attn_avg[b,q,k] = (1/H) sum_h exp(s_h(q,k) - m[b,h,q]) / l[b,h,q] ====
__global__ __launch_bounds__(64) void attn_avg_k(
    const float* __restrict__ Qp, const float* __restrict__ Kp,
    const float* __restrict__ mbuf, const float* __restrict__ lbuf,
    const int* __restrict__ mask, float* __restrict__ aout) {
  const int tid = threadIdx.x;
  const int k0 = blockIdx.x * 64;
  const int q0 = blockIdx.y * 64;
  const int b  = blockIdx.z;
  __shared__ __align__(16) float Ks[64 * 64];
  __shared__ float accL[64 * 65];

  for (int j = 0; j < 64; j++) accL[tid * 65 + j] = 0.f;

  for (int h = 0; h < NHEAD; h++) {
    __syncthreads();
#pragma unroll 4
    for (int i = 0; i < 16; i++) {
      const int idx = tid + i * 64;
      const size_t base =
          ((size_t)(b * SLEN + k0 + (idx >> 4))) * DMODEL + h * DHEAD + (idx & 15) * 4;
      ((float4*)Ks)[idx] = *(const float4*)(Kp + base);
    }
    __syncthreads();
    float4 qf[16];
    const float* qrow = Qp + ((size_t)(b * SLEN + q0 + tid)) * DMODEL + h * DHEAD;
#pragma unroll
    for (int i = 0; i < 16; i++) qf[i] = ((const float4*)qrow)[i];
    const int qi = (b * NHEAD + h) * SLEN + q0 + tid;
    const float mm = mbuf[qi];
    const float il = 1.f / lbuf[qi];
    for (int j = 0; j < 64; j++) {
      if (mask[b * SLEN + k0 + j] == 0) continue;
      const float4* kr = (const float4*)(Ks + j * 64);
      float s = 0.f;
#pragma unroll
      for (int i = 0; i < 16; i++) {
        const float4 kv = kr[i];
        s = fmaf(qf[i].x, kv.x, s);
        s = fmaf(qf[i].y, kv.y, s);
        s = fmaf(qf[i].z, kv.z, s);
        s = fmaf(qf[i].w, kv.w, s);
      }
      s *= 0.125f;
      accL[tid * 65 + j] += __expf(s - mm) * il;
    }
  }
  const float inv_h = 1.f / NHEAD;
  float* arow = aout + ((size_t)(b * SLEN + q0 + tid)) * SLEN + k0;
#pragma unroll
  for (int j4 = 0; j4 < 16; j4++) {
    float4 ov;
    ov.x = accL[tid * 65 + j4 * 4 + 0] * inv_h;
    ov.y = accL[tid * 65 + j4 * 4 + 1] * inv_h;
    ov.z = accL[tid * 65 + j4 * 4 + 2] * inv_h;
    ov.w = accL[tid * 65 + j4 * 4 + 3] * inv_h;
    ((float4*)arow)[j4] = ov;
  }
}

extern "C" void kernel_launch(void* const* d_in, const int* in_sizes, int n_in,
                              void* d_out, int out_size, void* d_ws, size_t ws_size,
                              hipStream_t stream) {
  const float* q   = (const float*)d_in[0];
  const float* k   = (const float*)d_in[1];
  const float* v   = (const float*)d_in[2];
  const float* Wq  = (const float*)d_in[3];
  const float* bq  = (const float*)d_in[4];
  const float* Wk  = (const float*)d_in[5];
  const float* bk  = (const float*)d_in[6];
  const float* Wv  = (const float*)d_in[7];
  const float* bv  = (const float*)d_in[8];
  const float* Wfc = (const float*)d_in[9];
  const float* bfc = (const float*)d_in[10];
  const int* mask  = (const int*)d_in[11];

  float* out      = (float*)d_out;                 // [B,S,2D]
  float* attn_avg = out + (size_t)MROWS * DOUT;    // [B,S,S]

  // Workspace (f32): Qp,Kp,Vp,att each MROWS*DMODEL; m,l each B*H*S.
  float* ws   = (float*)d_ws;
  float* Qp   = ws;
  float* Kp   = Qp + (size_t)MROWS * DMODEL;
  float* Vp   = Kp + (size_t)MROWS * DMODEL;
  float* att  = Vp + (size_t)MROWS * DMODEL;
  float* mbuf = att + (size_t)MROWS * DMODEL;
  float* lbuf = mbuf + (size_t)BATCH * NHEAD * SLEN;

  // Scratch in the d_out arena (dead before attn_avg/FC write their regions):
  // opart bf16 [B,H,NSPLIT,S,DHEAD] = 33.5 MB; mpart/lpart f32 = 2 MB each.
  unsigned short* opart = (unsigned short*)d_out;
  float* mpart = (float*)((char*)d_out + (size_t)BATCH * NHEAD * NSPLIT * SLEN * DHEAD * 2);
  float* lpart = mpart + (size_t)BATCH * NHEAD * NSPLIT * SLEN;

  // 1) projections
  gemm_bias_k<<<dim3(DMODEL / 64, MROWS / 64), dim3(256), 0, stream>>>(
      q, Wq, bq, Qp, MROWS, DMODEL, DMODEL);
  gemm_bias_k<<<dim3(DMODEL / 64, MROWS / 64), dim3(256), 0, stream>>>(
      k, Wk, bk, Kp, MROWS, DMODEL, DMODEL);
  gemm_bias_k<<<dim3(DMODEL / 64, MROWS / 64), dim3(256), 0, stream>>>(
      v, Wv, bv, Vp, MROWS, 2 * DMODEL, DMODEL);
  // 2) flash attention, k-split x4 -> partials in d_out arena
  flash_part_k<<<dim3(NHEAD * NSPLIT, SLEN / 64, BATCH), dim3(64), 0, stream>>>(
      Qp, Kp, Vp, mask, opart, mpart, lpart);
  // 2b) combine partials -> att + final (m,l)
  flash_combine_k<<<dim3(SLEN, NHEAD, BATCH), dim3(64), 0, stream>>>(
      opart, mpart, lpart, att, mbuf, lbuf);
  // 3) head-averaged attention map
  attn_avg_k<<<dim3(SLEN / 64, SLEN / 64, BATCH), dim3(64), 0, stream>>>(
      Qp, Kp, mbuf, lbuf, mask, attn_avg);
  // 4) output FC
  gemm_bias_k<<<dim3(DOUT / 64, MROWS / 64), dim3(256), 0, stream>>>(
      att, Wfc, bfc, out, MROWS, DMODEL, DOUT);
}

// Round 3
// 491.809 us; speedup vs baseline: 6.5702x; 5.5596x over previous
//
#include <hip/hip_runtime.h>
#include <math.h>

#define BATCH   2
#define SLEN    2048
#define DMODEL  1024
#define NHEAD   16
#define DHEAD   64
#define DOUT    2048
#define MROWS   (BATCH * SLEN)   // 4096

typedef short bf16x8 __attribute__((ext_vector_type(8)));
typedef float floatx4 __attribute__((ext_vector_type(4)));

static __device__ __forceinline__ unsigned short f2bf(float f) {
  unsigned u = __float_as_uint(f);
  u += 0x7fff + ((u >> 16) & 1);
  return (unsigned short)(u >> 16);
}

static __device__ __forceinline__ floatx4 mfma16(bf16x8 a, bf16x8 b, floatx4 c) {
  return __builtin_amdgcn_mfma_f32_16x16x32_bf16(a, b, c, 0, 0, 0);
}

// ===================== f32 -> bf16 elementwise convert ======================
__global__ __launch_bounds__(256) void conv_bf16_k(
    const float* __restrict__ in, unsigned short* __restrict__ out, int n8) {
  const int i = blockIdx.x * 256 + threadIdx.x;
  if (i >= n8) return;
  const float4 a = ((const float4*)in)[i * 2];
  const float4 b = ((const float4*)in)[i * 2 + 1];
  ushort4 u0, u1;
  u0.x = f2bf(a.x); u0.y = f2bf(a.y); u0.z = f2bf(a.z); u0.w = f2bf(a.w);
  u1.x = f2bf(b.x); u1.y = f2bf(b.y); u1.z = f2bf(b.z); u1.w = f2bf(b.w);
  ((ushort4*)out)[i * 2] = u0;
  ((ushort4*)out)[i * 2 + 1] = u1;
}

// ============== W[K][N] f32 -> WT[N][K] bf16 (32x32 LDS tiles) ==============
__global__ __launch_bounds__(256) void wtrans_k(
    const float* __restrict__ W, unsigned short* __restrict__ WT, int K, int N) {
  __shared__ float T[32][33];
  const int t = threadIdx.x;
  const int n0 = blockIdx.x * 32, k0 = blockIdx.y * 32;
  {
    const int r = t >> 3, c4 = (t & 7) * 4;
    const float4 w = *(const float4*)(W + (size_t)(k0 + r) * N + n0 + c4);
    T[r][c4 + 0] = w.x; T[r][c4 + 1] = w.y; T[r][c4 + 2] = w.z; T[r][c4 + 3] = w.w;
  }
  __syncthreads();
  {
    const int n = t >> 3, k4 = (t & 7) * 4;
    ushort4 u;
    u.x = f2bf(T[k4 + 0][n]); u.y = f2bf(T[k4 + 1][n]);
    u.z = f2bf(T[k4 + 2][n]); u.w = f2bf(T[k4 + 3][n]);
    *(ushort4*)(WT + (size_t)(n0 + n) * K + k0 + k4) = u;
  }
}

// ====== MFMA GEMM: C[M][N] = A[M][K](bf16) x BT[N][K](bf16)^T + bias ========
// 128x128 tile, BK=32, 256 thr = 4 waves, each wave 64x64 (4x4 of 16x16).
template <int OUTF32>
__global__ __launch_bounds__(256) void mfma_gemm_k(
    const unsigned short* __restrict__ A, const unsigned short* __restrict__ BT,
    const float* __restrict__ bias, void* __restrict__ C, int M, int K, int N) {
  __shared__ unsigned short As[128][40];  // [m][k], +8 pad
  __shared__ unsigned short Bs[128][40];  // [n][k]
  const int t = threadIdx.x;
  const int w = t >> 6, l = t & 63, quad = l >> 4, lq = l & 15;
  const int row0 = blockIdx.y * 128, col0 = blockIdx.x * 128;
  const int wm = (w >> 1) * 64, wn = (w & 1) * 64;

  floatx4 acc[4][4];
#pragma unroll
  for (int i = 0; i < 4; i++)
#pragma unroll
    for (int j = 0; j < 4; j++) acc[i][j] = (floatx4){0.f, 0.f, 0.f, 0.f};

  const int srow = t >> 1, shalf = (t & 1) * 16;
  const unsigned short* Ag = A + (size_t)(row0 + srow) * K + shalf;
  const unsigned short* Bg = BT + (size_t)(col0 + srow) * K + shalf;

  for (int kt = 0; kt < K; kt += 32) {
    *(bf16x8*)&As[srow][shalf]     = *(const bf16x8*)(Ag + kt);
    *(bf16x8*)&As[srow][shalf + 8] = *(const bf16x8*)(Ag + kt + 8);
    *(bf16x8*)&Bs[srow][shalf]     = *(const bf16x8*)(Bg + kt);
    *(bf16x8*)&Bs[srow][shalf + 8] = *(const bf16x8*)(Bg + kt + 8);
    __syncthreads();
    bf16x8 af[4], bfr[4];
#pragma unroll
    for (int ti = 0; ti < 4; ti++)
      af[ti] = *(const bf16x8*)&As[wm + ti * 16 + lq][quad * 8];
#pragma unroll
    for (int tj = 0; tj < 4; tj++)
      bfr[tj] = *(const bf16x8*)&Bs[wn + tj * 16 + lq][quad * 8];
#pragma unroll
    for (int ti = 0; ti < 4; ti++)
#pragma unroll
      for (int tj = 0; tj < 4; tj++)
        acc[ti][tj] = mfma16(af[ti], bfr[tj], acc[ti][tj]);
    __syncthreads();
  }

#pragma unroll
  for (int tj = 0; tj < 4; tj++) {
    const int col = col0 + wn + tj * 16 + lq;
    const float bv = bias[col];
#pragma unroll
    for (int ti = 0; ti < 4; ti++) {
#pragma unroll
      for (int r = 0; r < 4; r++) {
        const int row = row0 + wm + ti * 16 + quad * 4 + r;
        const float v = acc[ti][tj][r] + bv;
        if (OUTF32)
          ((float*)C)[(size_t)row * N + col] = v;
        else
          ((unsigned short*)C)[(size_t)row * N + col] = f2bf(v);
      }
    }
  }
}

// ================== Flash attention, MFMA, per (b,h,q-tile64) ===============
// 4 waves; wave w owns q rows [q0+w*16, +16). K-tile 64 staged row-major,
// V-tile staged transposed [d][kk]; P transposed C->A layout via per-wave LDS.
__global__ __launch_bounds__(256) void flash_mfma_k(
    const unsigned short* __restrict__ Qp, const unsigned short* __restrict__ Kp,
    const unsigned short* __restrict__ Vp, const int* __restrict__ mask,
    unsigned short* __restrict__ att, float* __restrict__ mbuf,
    float* __restrict__ lbuf) {
  __shared__ unsigned short Ks[64][72];      // [kk][d]
  __shared__ unsigned short Vt[64][72];      // [d][kk]
  __shared__ unsigned short Ps[4][16][72];   // per-wave [q][kk]
  const int t = threadIdx.x;
  const int w = t >> 6, l = t & 63, quad = l >> 4, lq = l & 15;
  const int q0 = blockIdx.x * 64, h = blockIdx.y, b = blockIdx.z;

  const unsigned short* qptr =
      Qp + (size_t)(b * SLEN + q0 + w * 16 + lq) * DMODEL + h * 64;
  bf16x8 aq0 = *(const bf16x8*)(qptr + quad * 8);
  bf16x8 aq1 = *(const bf16x8*)(qptr + 32 + quad * 8);

  floatx4 acc_o[4];
#pragma unroll
  for (int dj = 0; dj < 4; dj++) acc_o[dj] = (floatx4){0.f, 0.f, 0.f, 0.f};
  float mrow[4] = {-1e30f, -1e30f, -1e30f, -1e30f};
  float lrow[4] = {0.f, 0.f, 0.f, 0.f};

  const int krow = t >> 2, kseg = (t & 3) * 16;

  for (int k0 = 0; k0 < SLEN; k0 += 64) {
    __syncthreads();
    // stage K row-major
    const unsigned short* kg =
        Kp + (size_t)(b * SLEN + k0 + krow) * DMODEL + h * 64 + kseg;
    *(bf16x8*)&Ks[krow][kseg]     = *(const bf16x8*)kg;
    *(bf16x8*)&Ks[krow][kseg + 8] = *(const bf16x8*)(kg + 8);
    // stage V transposed
#pragma unroll
    for (int it = 0; it < 2; it++) {
      const int id = it * 256 + t;
      const int kk = id & 63, dg = id >> 6;
      bf16x8 vv = *(const bf16x8*)(Vp + (size_t)(b * SLEN + k0 + kk) * DMODEL +
                                   h * 64 + dg * 8);
#pragma unroll
      for (int j = 0; j < 8; j++) Vt[dg * 8 + j][kk] = (unsigned short)vv[j];
    }
    __syncthreads();

    // S = Q K^T / 8 with mask
    floatx4 s[4];
    int mk[4];
#pragma unroll
    for (int ti = 0; ti < 4; ti++) {
      bf16x8 bk0 = *(const bf16x8*)&Ks[ti * 16 + lq][quad * 8];
      bf16x8 bk1 = *(const bf16x8*)&Ks[ti * 16 + lq][32 + quad * 8];
      floatx4 z = (floatx4){0.f, 0.f, 0.f, 0.f};
      z = mfma16(aq0, bk0, z);
      z = mfma16(aq1, bk1, z);
      s[ti] = z;
      mk[ti] = mask[b * SLEN + k0 + ti * 16 + lq];
    }
#pragma unroll
    for (int ti = 0; ti < 4; ti++)
#pragma unroll
      for (int r = 0; r < 4; r++)
        s[ti][r] = mk[ti] ? s[ti][r] * 0.125f : -3.0e38f;

    float alpha[4];
#pragma unroll
    for (int r = 0; r < 4; r++) {
      float mx = fmaxf(fmaxf(s[0][r], s[1][r]), fmaxf(s[2][r], s[3][r]));
      mx = fmaxf(mx, __shfl_xor(mx, 1));
      mx = fmaxf(mx, __shfl_xor(mx, 2));
      mx = fmaxf(mx, __shfl_xor(mx, 4));
      mx = fmaxf(mx, __shfl_xor(mx, 8));
      const float mn = fmaxf(mrow[r], mx);
      alpha[r] = __expf(mrow[r] - mn);
      mrow[r] = mn;
    }
#pragma unroll
    for (int ti = 0; ti < 4; ti++)
#pragma unroll
      for (int r = 0; r < 4; r++) s[ti][r] = __expf(s[ti][r] - mrow[r]);
#pragma unroll
    for (int r = 0; r < 4; r++) {
      float rs = s[0][r] + s[1][r] + s[2][r] + s[3][r];
      rs += __shfl_xor(rs, 1);
      rs += __shfl_xor(rs, 2);
      rs += __shfl_xor(rs, 4);
      rs += __shfl_xor(rs, 8);
      lrow[r] = lrow[r] * alpha[r] + rs;
    }
#pragma unroll
    for (int dj = 0; dj < 4; dj++)
#pragma unroll
      for (int r = 0; r < 4; r++) acc_o[dj][r] *= alpha[r];

    // P: C-layout -> LDS -> A-layout (per-wave, no barrier needed)
#pragma unroll
    for (int ti = 0; ti < 4; ti++)
#pragma unroll
      for (int r = 0; r < 4; r++)
        Ps[w][quad * 4 + r][ti * 16 + lq] = f2bf(s[ti][r]);
    bf16x8 ap0 = *(const bf16x8*)&Ps[w][lq][quad * 8];
    bf16x8 ap1 = *(const bf16x8*)&Ps[w][lq][32 + quad * 8];
#pragma unroll
    for (int dj = 0; dj < 4; dj++) {
      bf16x8 bv0 = *(const bf16x8*)&Vt[dj * 16 + lq][quad * 8];
      bf16x8 bv1 = *(const bf16x8*)&Vt[dj * 16 + lq][32 + quad * 8];
      acc_o[dj] = mfma16(ap0, bv0, acc_o[dj]);
      acc_o[dj] = mfma16(ap1, bv1, acc_o[dj]);
    }
  }

  float inv[4];
#pragma unroll
  for (int r = 0; r < 4; r++) inv[r] = (lrow[r] > 0.f) ? 1.f / lrow[r] : 0.f;
#pragma unroll
  for (int dj = 0; dj < 4; dj++)
#pragma unroll
    for (int r = 0; r < 4; r++)
      att[(size_t)(b * SLEN + q0 + w * 16 + quad * 4 + r) * DMODEL + h * 64 +
          dj * 16 + lq] = f2bf(acc_o[dj][r] * inv[r]);
  if (lq == 0) {
#pragma unroll
    for (int r = 0; r < 4; r++) {
      const int qi = (b * NHEAD + h) * SLEN + q0 + w * 16 + quad * 4 + r;
      mbuf[qi] = mrow[r];
      lbuf[qi] = lrow[r];
    }
  }
}

// ========== attn_avg: recompute scores via MFMA using saved (m,l) ===========
__global__ __launch_bounds__(256) void attn_avg_mfma_k(
    const unsigned short* __restrict__ Qp, const unsigned short* __restrict__ Kp,
    const float* __restrict__ mbuf, const float* __restrict__ lbuf,
    const int* __restrict__ mask, float* __restrict__ aout) {
  __shared__ unsigned short Ks[64][72];
  const int t = threadIdx.x;
  const int w = t >> 6, l = t & 63, quad = l >> 4, lq = l & 15;
  const int k0 = blockIdx.x * 64, q0 = blockIdx.y * 64, b = blockIdx.z;

  floatx4 acc[4];
#pragma unroll
  for (int ti = 0; ti < 4; ti++) acc[ti] = (floatx4){0.f, 0.f, 0.f, 0.f};
  int mk[4];
#pragma unroll
  for (int ti = 0; ti < 4; ti++) mk[ti] = mask[b * SLEN + k0 + ti * 16 + lq];

  const unsigned short* qbase =
      Qp + (size_t)(b * SLEN + q0 + w * 16 + lq) * DMODEL;
  const int krow = t >> 2, kseg = (t & 3) * 16;

  for (int h = 0; h < NHEAD; h++) {
    __syncthreads();
    const unsigned short* kg =
        Kp + (size_t)(b * SLEN + k0 + krow) * DMODEL + h * 64 + kseg;
    *(bf16x8*)&Ks[krow][kseg]     = *(const bf16x8*)kg;
    *(bf16x8*)&Ks[krow][kseg + 8] = *(const bf16x8*)(kg + 8);
    __syncthreads();

    bf16x8 aq0 = *(const bf16x8*)(qbase + h * 64 + quad * 8);
    bf16x8 aq1 = *(const bf16x8*)(qbase + h * 64 + 32 + quad * 8);
    float mr[4], ilr[4];
#pragma unroll
    for (int r = 0; r < 4; r++) {
      const int qi = (b * NHEAD + h) * SLEN + q0 + w * 16 + quad * 4 + r;
      mr[r] = mbuf[qi];
      const float lv = lbuf[qi];
      ilr[r] = (lv > 0.f) ? 1.f / lv : 0.f;
    }
#pragma unroll
    for (int ti = 0; ti < 4; ti++) {
      bf16x8 bk0 = *(const bf16x8*)&Ks[ti * 16 + lq][quad * 8];
      bf16x8 bk1 = *(const bf16x8*)&Ks[ti * 16 + lq][32 + quad * 8];
      floatx4 z = (floatx4){0.f, 0.f, 0.f, 0.f};
      z = mfma16(aq0, bk0, z);
      z = mfma16(aq1, bk1, z);
#pragma unroll
      for (int r = 0; r < 4; r++)
        acc[ti][r] += mk[ti] ? __expf(z[r] * 0.125f - mr[r]) * ilr[r] : 0.f;
    }
  }
  const float ih = 1.f / NHEAD;
#pragma unroll
  for (int ti = 0; ti < 4; ti++)
#pragma unroll
    for (int r = 0; r < 4; r++)
      aout[(size_t)(b * SLEN + q0 + w * 16 + quad * 4 + r) * SLEN + k0 +
           ti * 16 + lq] = acc[ti][r] * ih;
}

extern "C" void kernel_launch(void* const* d_in, const int* in_sizes, int n_in,
                              void* d_out, int out_size, void* d_ws, size_t ws_size,
                              hipStream_t stream) {
  const float* q   = (const float*)d_in[0];
  const float* k   = (const float*)d_in[1];
  const float* v   = (const float*)d_in[2];
  const float* Wq  = (const float*)d_in[3];
  const float* bq  = (const float*)d_in[4];
  const float* Wk  = (const float*)d_in[5];
  const float* bk  = (const float*)d_in[6];
  const float* Wv  = (const float*)d_in[7];
  const float* bv  = (const float*)d_in[8];
  const float* Wfc = (const float*)d_in[9];
  const float* bfc = (const float*)d_in[10];
  const int* mask  = (const int*)d_in[11];

  float* out      = (float*)d_out;                       // [B,S,2D]
  float* attn_avg = out + (size_t)MROWS * DOUT;          // [B,S,S]

  // bf16 copies of activations live in the d_out `out` region (dead before
  // the FC writes it): qb 4M + kb 4M + vb 8M elems = 33554432 B exactly.
  unsigned short* qb = (unsigned short*)d_out;
  unsigned short* kb = qb + (1u << 22);
  unsigned short* vb = kb + (1u << 22);

  // ws (bf16 elems): WqT 1M | WkT 1M | WvT 2M | WfcT 2M | Qp 4M | Kp 4M |
  // Vp 4M | att 4M | mbuf/lbuf f32
  unsigned short* wsb  = (unsigned short*)d_ws;
  unsigned short* WqT  = wsb;
  unsigned short* WkT  = wsb + (1u << 20);
  unsigned short* WvT  = wsb + (2u << 20);
  unsigned short* WfcT = wsb + (4u << 20);
  unsigned short* Qp   = wsb + (6u << 20);
  unsigned short* Kp   = Qp + (1u << 22);
  unsigned short* Vp   = Kp + (1u << 22);
  unsigned short* att  = Vp + (1u << 22);
  float* mbuf = (float*)(att + (1u << 22));
  float* lbuf = mbuf + BATCH * NHEAD * SLEN;

  // 0) convert activations to bf16
  conv_bf16_k<<<dim3(2048), dim3(256), 0, stream>>>(q, qb, (1 << 22) / 8);
  conv_bf16_k<<<dim3(2048), dim3(256), 0, stream>>>(k, kb, (1 << 22) / 8);
  conv_bf16_k<<<dim3(4096), dim3(256), 0, stream>>>(v, vb, (1 << 23) / 8);
  // 0b) transpose + convert weights -> [N][K] bf16
  wtrans_k<<<dim3(32, 32), dim3(256), 0, stream>>>(Wq, WqT, DMODEL, DMODEL);
  wtrans_k<<<dim3(32, 32), dim3(256), 0, stream>>>(Wk, WkT, DMODEL, DMODEL);
  wtrans_k<<<dim3(32, 64), dim3(256), 0, stream>>>(Wv, WvT, 2 * DMODEL, DMODEL);
  wtrans_k<<<dim3(64, 32), dim3(256), 0, stream>>>(Wfc, WfcT, DMODEL, DOUT);
  // 1) projections (bf16 out)
  mfma_gemm_k<0><<<dim3(8, 32), dim3(256), 0, stream>>>(qb, WqT, bq, Qp,
                                                        MROWS, DMODEL, DMODEL);
  mfma_gemm_k<0><<<dim3(8, 32), dim3(256), 0, stream>>>(kb, WkT, bk, Kp,
                                                        MROWS, DMODEL, DMODEL);
  mfma_gemm_k<0><<<dim3(8, 32), dim3(256), 0, stream>>>(vb, WvT, bv, Vp,
                                                        MROWS, 2 * DMODEL, DMODEL);
  // 2) flash attention -> att(bf16), mbuf, lbuf
  flash_mfma_k<<<dim3(SLEN / 64, NHEAD, BATCH), dim3(256), 0, stream>>>(
      Qp, Kp, Vp, mask, att, mbuf, lbuf);
  // 3) head-averaged attention map (f32, overwrites vb region — dead)
  attn_avg_mfma_k<<<dim3(SLEN / 64, SLEN / 64, BATCH), dim3(256), 0, stream>>>(
      Qp, Kp, mbuf, lbuf, mask, attn_avg);
  // 4) output FC (f32 out, overwrites qb/kb region — dead)
  mfma_gemm_k<1><<<dim3(16, 32), dim3(256), 0, stream>>>(att, WfcT, bfc, out,
                                                         MROWS, DMODEL, DOUT);
}

// Round 4
// 397.641 us; speedup vs baseline: 8.1261x; 1.2368x over previous
//
#include <hip/hip_runtime.h>
#include <math.h>

#define BATCH   2
#define SLEN    2048
#define DMODEL  1024
#define NHEAD   16
#define DHEAD   64
#define DOUT    2048
#define MROWS   (BATCH * SLEN)   // 4096
#define NSPLIT  2
#define KSPAN   (SLEN / NSPLIT)  // 1024

typedef short bf16x8 __attribute__((ext_vector_type(8)));
typedef float floatx4 __attribute__((ext_vector_type(4)));

static __device__ __forceinline__ unsigned short f2bf(float f) {
  unsigned u = __float_as_uint(f);
  u += 0x7fff + ((u >> 16) & 1);
  return (unsigned short)(u >> 16);
}
static __device__ __forceinline__ float bf2f(unsigned short s) {
  return __uint_as_float(((unsigned)s) << 16);
}
static __device__ __forceinline__ floatx4 mfma16(bf16x8 a, bf16x8 b, floatx4 c) {
  return __builtin_amdgcn_mfma_f32_16x16x32_bf16(a, b, c, 0, 0, 0);
}
// async global->LDS, 16B per lane; LDS dest = uniform base + lane*16
static __device__ __forceinline__ void gll16(const void* g, void* l) {
  __builtin_amdgcn_global_load_lds(
      (const __attribute__((address_space(1))) unsigned int*)g,
      (__attribute__((address_space(3))) unsigned int*)l, 16, 0, 0);
}

// ===================== f32 -> bf16 elementwise convert ======================
__global__ __launch_bounds__(256) void conv_bf16_k(
    const float* __restrict__ in, unsigned short* __restrict__ out, int n8) {
  const int i = blockIdx.x * 256 + threadIdx.x;
  if (i >= n8) return;
  const float4 a = ((const float4*)in)[i * 2];
  const float4 b = ((const float4*)in)[i * 2 + 1];
  ushort4 u0, u1;
  u0.x = f2bf(a.x); u0.y = f2bf(a.y); u0.z = f2bf(a.z); u0.w = f2bf(a.w);
  u1.x = f2bf(b.x); u1.y = f2bf(b.y); u1.z = f2bf(b.z); u1.w = f2bf(b.w);
  ((ushort4*)out)[i * 2] = u0;
  ((ushort4*)out)[i * 2 + 1] = u1;
}

// ============== W[K][N] f32 -> WT[N][K] bf16 (32x32 LDS tiles) ==============
__global__ __launch_bounds__(256) void wtrans_k(
    const float* __restrict__ W, unsigned short* __restrict__ WT, int K, int N) {
  __shared__ float T[32][33];
  const int t = threadIdx.x;
  const int n0 = blockIdx.x * 32, k0 = blockIdx.y * 32;
  {
    const int r = t >> 3, c4 = (t & 7) * 4;
    const float4 w = *(const float4*)(W + (size_t)(k0 + r) * N + n0 + c4);
    T[r][c4 + 0] = w.x; T[r][c4 + 1] = w.y; T[r][c4 + 2] = w.z; T[r][c4 + 3] = w.w;
  }
  __syncthreads();
  {
    const int n = t >> 3, k4 = (t & 7) * 4;
    ushort4 u;
    u.x = f2bf(T[k4 + 0][n]); u.y = f2bf(T[k4 + 1][n]);
    u.z = f2bf(T[k4 + 2][n]); u.w = f2bf(T[k4 + 3][n]);
    *(ushort4*)(WT + (size_t)(n0 + n) * K + k0 + k4) = u;
  }
}

// ====== MFMA GEMM body: C = A[M][K] x BT[N][K]^T + bias. 128x64 tile, BK=64,
// 256 thr = 4 waves (wave = 64x32 = 4x2 frags). global_load_lds staging into
// XOR-swizzled LDS (16B chunk g stored at g^(row&7)) -> conflict-free b128.
// MODE: 0 = bf16 row-major, 1 = f32 row-major, 2 = bf16 transposed C^T[N][M].
template <int MODE>
static __device__ __forceinline__ void gemm_body(
    const unsigned short* __restrict__ A, const unsigned short* __restrict__ BT,
    const float* __restrict__ bias, void* __restrict__ C, int M, int K, int N,
    int row0, int col0) {
  __shared__ unsigned short As[128 * 64];
  __shared__ unsigned short Bs[64 * 64];
  const int t = threadIdx.x;
  const int w = t >> 6, l = t & 63, quad = l >> 4, lq = l & 15;
  const int wm = (w >> 1) * 64, wn = (w & 1) * 32;

  // staging source pointers (per-lane, swizzled chunk)
  const unsigned short* aS[4];
#pragma unroll
  for (int jj = 0; jj < 4; jj++) {
    const int inst = w * 4 + jj;
    const int m = inst * 8 + (l >> 3);
    const int g = l & 7;
    aS[jj] = A + (size_t)(row0 + m) * K + ((g ^ (m & 7)) << 3);
  }
  const unsigned short* bS[2];
#pragma unroll
  for (int jj = 0; jj < 2; jj++) {
    const int inst = w * 2 + jj;
    const int n = inst * 8 + (l >> 3);
    const int g = l & 7;
    bS[jj] = BT + (size_t)(col0 + n) * K + ((g ^ (n & 7)) << 3);
  }

  floatx4 acc[4][2];
#pragma unroll
  for (int i = 0; i < 4; i++)
#pragma unroll
    for (int j = 0; j < 2; j++) acc[i][j] = (floatx4){0.f, 0.f, 0.f, 0.f};

  for (int kt = 0; kt < K; kt += 64) {
#pragma unroll
    for (int jj = 0; jj < 4; jj++)
      gll16(aS[jj] + kt, As + (w * 4 + jj) * 512);
#pragma unroll
    for (int jj = 0; jj < 2; jj++)
      gll16(bS[jj] + kt, Bs + (w * 2 + jj) * 512);
    __syncthreads();  // drains vmcnt(0) incl. LDS-DMA before reads

    bf16x8 af[4][2], bfr[2][2];
#pragma unroll
    for (int ti = 0; ti < 4; ti++) {
      const int m = wm + ti * 16 + lq;
#pragma unroll
      for (int h = 0; h < 2; h++)
        af[ti][h] = *(const bf16x8*)(As + m * 64 + (((h * 4 + quad) ^ (m & 7)) << 3));
    }
#pragma unroll
    for (int tj = 0; tj < 2; tj++) {
      const int n = wn + tj * 16 + lq;
#pragma unroll
      for (int h = 0; h < 2; h++)
        bfr[tj][h] = *(const bf16x8*)(Bs + n * 64 + (((h * 4 + quad) ^ (n & 7)) << 3));
    }
#pragma unroll
    for (int ti = 0; ti < 4; ti++)
#pragma unroll
      for (int tj = 0; tj < 2; tj++) {
        acc[ti][tj] = mfma16(af[ti][0], bfr[tj][0], acc[ti][tj]);
        acc[ti][tj] = mfma16(af[ti][1], bfr[tj][1], acc[ti][tj]);
      }
    __syncthreads();
  }

#pragma unroll
  for (int tj = 0; tj < 2; tj++) {
    const int col = col0 + wn + tj * 16 + lq;
    const float bv = bias[col];
    if (MODE == 2) {
#pragma unroll
      for (int ti = 0; ti < 4; ti++) {
        ushort4 u;
        u.x = f2bf(acc[ti][tj][0] + bv);
        u.y = f2bf(acc[ti][tj][1] + bv);
        u.z = f2bf(acc[ti][tj][2] + bv);
        u.w = f2bf(acc[ti][tj][3] + bv);
        *(ushort4*)((unsigned short*)C + (size_t)col * M + row0 + wm + ti * 16 +
                    quad * 4) = u;
      }
    } else {
#pragma unroll
      for (int ti = 0; ti < 4; ti++)
#pragma unroll
        for (int r = 0; r < 4; r++) {
          const int row = row0 + wm + ti * 16 + quad * 4 + r;
          const float vv = acc[ti][tj][r] + bv;
          if (MODE == 1)
            ((float*)C)[(size_t)row * N + col] = vv;
          else
            ((unsigned short*)C)[(size_t)row * N + col] = f2bf(vv);
        }
    }
  }
}

// Q & K projections fused in one launch (blockIdx.z selects)
__global__ __launch_bounds__(256) void qkproj_k(
    const unsigned short* qb, const unsigned short* kb,
    const unsigned short* WqT, const unsigned short* WkT,
    const float* bq, const float* bk,
    unsigned short* Qp, unsigned short* Kp) {
  const int z = blockIdx.z;
  gemm_body<0>(z ? kb : qb, z ? WkT : WqT, z ? bk : bq, z ? Kp : Qp,
               MROWS, DMODEL, DMODEL, blockIdx.y * 128, blockIdx.x * 64);
}
// V projection, transposed output VT[N][M]
__global__ __launch_bounds__(256) void vproj_k(
    const unsigned short* vb, const unsigned short* WvT, const float* bv,
    unsigned short* VT) {
  gemm_body<2>(vb, WvT, bv, VT, MROWS, 2 * DMODEL, DMODEL,
               blockIdx.y * 128, blockIdx.x * 64);
}
// output FC, f32 out
__global__ __launch_bounds__(256) void fc_k(
    const unsigned short* att, const unsigned short* WfcT, const float* bfc,
    float* out) {
  gemm_body<1>(att, WfcT, bfc, out, MROWS, DMODEL, DOUT,
               blockIdx.y * 128, blockIdx.x * 64);
}

// ============== Flash attention, m=0 softmax, k-split x NSPLIT ==============
// Block = (b, h, split, q-tile64), 4 waves, wave owns 16 q rows.
// P tiles independent (no rescaling) -> pure GEMM accumulate; l deferred.
__global__ __launch_bounds__(256) void flash_mfma_k(
    const unsigned short* __restrict__ Qp, const unsigned short* __restrict__ Kp,
    const unsigned short* __restrict__ VT, const int* __restrict__ mask,
    unsigned short* __restrict__ Opart, float* __restrict__ Lpart) {
  __shared__ unsigned short Ks[64 * 88];     // [kk][d], stride 88 conflict-free
  __shared__ unsigned short Vs[64 * 88];     // [d][kk]  (from VT, no transpose)
  __shared__ unsigned short Ps[4 * 16 * 64]; // per-wave, XOR-swizzled cols
  const int t = threadIdx.x;
  const int w = t >> 6, l = t & 63, quad = l >> 4, lq = l & 15;
  const int q0 = blockIdx.x * 64;
  const int h = blockIdx.y >> 1, split = blockIdx.y & 1;
  const int b = blockIdx.z;

  const unsigned short* qptr =
      Qp + (size_t)(b * SLEN + q0 + w * 16 + lq) * DMODEL + h * 64;
  const bf16x8 aq0 = *(const bf16x8*)(qptr + quad * 8);
  const bf16x8 aq1 = *(const bf16x8*)(qptr + 32 + quad * 8);

  floatx4 acc_o[4];
#pragma unroll
  for (int dj = 0; dj < 4; dj++) acc_o[dj] = (floatx4){0.f, 0.f, 0.f, 0.f};
  float lsum[4] = {0.f, 0.f, 0.f, 0.f};

  const int krow = t >> 2, kseg = (t & 3) * 16;

  for (int k0 = split * KSPAN; k0 < split * KSPAN + KSPAN; k0 += 64) {
    __syncthreads();
    const unsigned short* kg =
        Kp + (size_t)(b * SLEN + k0 + krow) * DMODEL + h * 64 + kseg;
    *(bf16x8*)&Ks[krow * 88 + kseg]     = *(const bf16x8*)kg;
    *(bf16x8*)&Ks[krow * 88 + kseg + 8] = *(const bf16x8*)(kg + 8);
#pragma unroll
    for (int p = 0; p < 2; p++) {
      const int d = (p * 256 + t) >> 3, s8 = (t & 7) * 8;
      *(bf16x8*)&Vs[d * 88 + s8] =
          *(const bf16x8*)(VT + (size_t)(h * 64 + d) * MROWS + b * SLEN + k0 + s8);
    }
    __syncthreads();

    // S = Q K^T, then P = mask ? exp(S/8) : 0   (m=0: scores bounded)
    floatx4 s[4];
    int mk[4];
#pragma unroll
    for (int ti = 0; ti < 4; ti++) {
      const bf16x8 bk0 = *(const bf16x8*)&Ks[(ti * 16 + lq) * 88 + quad * 8];
      const bf16x8 bk1 = *(const bf16x8*)&Ks[(ti * 16 + lq) * 88 + 32 + quad * 8];
      floatx4 z = (floatx4){0.f, 0.f, 0.f, 0.f};
      z = mfma16(aq0, bk0, z);
      z = mfma16(aq1, bk1, z);
      s[ti] = z;
      mk[ti] = mask[b * SLEN + k0 + ti * 16 + lq];
    }
#pragma unroll
    for (int ti = 0; ti < 4; ti++)
#pragma unroll
      for (int r = 0; r < 4; r++) {
        float e = __expf(s[ti][r] * 0.125f);
        e = mk[ti] ? e : 0.f;
        s[ti][r] = e;
        lsum[r] += e;
      }
    // P: C-layout -> swizzled LDS -> A-layout. col' = (k + 8*q) & 63.
#pragma unroll
    for (int ti = 0; ti < 4; ti++)
#pragma unroll
      for (int r = 0; r < 4; r++) {
        const int qq = quad * 4 + r;
        Ps[w * 1024 + qq * 64 + ((ti * 16 + lq + qq * 8) & 63)] = f2bf(s[ti][r]);
      }
    const bf16x8 ap0 =
        *(const bf16x8*)&Ps[w * 1024 + lq * 64 + 8 * ((quad + lq) & 7)];
    const bf16x8 ap1 =
        *(const bf16x8*)&Ps[w * 1024 + lq * 64 + 8 * ((quad + lq + 4) & 7)];
#pragma unroll
    for (int dj = 0; dj < 4; dj++) {
      const bf16x8 bv0 = *(const bf16x8*)&Vs[(dj * 16 + lq) * 88 + quad * 8];
      const bf16x8 bv1 = *(const bf16x8*)&Vs[(dj * 16 + lq) * 88 + 32 + quad * 8];
      acc_o[dj] = mfma16(ap0, bv0, acc_o[dj]);
      acc_o[dj] = mfma16(ap1, bv1, acc_o[dj]);
    }
  }

  // reduce l over lq (cols) once, at the end
#pragma unroll
  for (int r = 0; r < 4; r++) {
    float v = lsum[r];
    v += __shfl_xor(v, 1);
    v += __shfl_xor(v, 2);
    v += __shfl_xor(v, 4);
    v += __shfl_xor(v, 8);
    lsum[r] = v;
  }

  // store unnormalized O partial (bf16) + l partial
  const size_t obase =
      (((size_t)split * BATCH + b) * NHEAD + h) * SLEN + q0 + w * 16;
#pragma unroll
  for (int dj = 0; dj < 4; dj++)
#pragma unroll
    for (int r = 0; r < 4; r++)
      Opart[(obase + quad * 4 + r) * DHEAD + dj * 16 + lq] = f2bf(acc_o[dj][r]);
  if (lq == 0) {
#pragma unroll
    for (int r = 0; r < 4; r++)
      Lpart[obase + quad * 4 + r] = lsum[r];
  }
}

// ======= combine split partials: att = (O0+O1)/(l0+l1), lbuf = l0+l1 ========
__global__ __launch_bounds__(256) void combine_k(
    const unsigned short* __restrict__ Opart, const float* __restrict__ Lpart,
    unsigned short* __restrict__ att, float* __restrict__ lbuf) {
  const int gid = blockIdx.x * 256 + threadIdx.x;  // over B*H*S*64/8
  const int row = gid >> 3;                        // (b*H+h)*S + q
  const int d8 = (gid & 7) * 8;
  const float l0 = Lpart[row];
  const float l1 = Lpart[(size_t)BATCH * NHEAD * SLEN + row];
  const float lt = l0 + l1;
  const float il = (lt > 0.f) ? 1.f / lt : 0.f;
  const bf16x8 o0 = *(const bf16x8*)(Opart + (size_t)row * DHEAD + d8);
  const bf16x8 o1 = *(const bf16x8*)(Opart + (size_t)(BATCH * NHEAD * SLEN) * DHEAD +
                                     (size_t)row * DHEAD + d8);
  const int b = row >> 15, hh = (row >> 11) & 15, q = row & 2047;
  unsigned short* dst = att + (size_t)(b * SLEN + q) * DMODEL + hh * 64 + d8;
  ushort4 u0, u1;
  float vv[8];
#pragma unroll
  for (int j = 0; j < 8; j++)
    vv[j] = (bf2f((unsigned short)o0[j]) + bf2f((unsigned short)o1[j])) * il;
  u0.x = f2bf(vv[0]); u0.y = f2bf(vv[1]); u0.z = f2bf(vv[2]); u0.w = f2bf(vv[3]);
  u1.x = f2bf(vv[4]); u1.y = f2bf(vv[5]); u1.z = f2bf(vv[6]); u1.w = f2bf(vv[7]);
  ((ushort4*)dst)[0] = u0;
  ((ushort4*)dst)[1] = u1;
  if ((gid & 7) == 0) lbuf[row] = lt;
}

// ======= attn_avg[b,q,k] = (1/H) sum_h exp(s_h(q,k)) / l[b,h,q]  (m=0) ======
__global__ __launch_bounds__(256) void attn_avg_mfma_k(
    const unsigned short* __restrict__ Qp, const unsigned short* __restrict__ Kp,
    const float* __restrict__ lbuf, const int* __restrict__ mask,
    float* __restrict__ aout) {
  __shared__ unsigned short Ks[64 * 88];
  const int t = threadIdx.x;
  const int w = t >> 6, l = t & 63, quad = l >> 4, lq = l & 15;
  const int k0 = blockIdx.x * 64, q0 = blockIdx.y * 64, b = blockIdx.z;

  floatx4 acc[4];
#pragma unroll
  for (int ti = 0; ti < 4; ti++) acc[ti] = (floatx4){0.f, 0.f, 0.f, 0.f};
  int mk[4];
#pragma unroll
  for (int ti = 0; ti < 4; ti++) mk[ti] = mask[b * SLEN + k0 + ti * 16 + lq];

  const unsigned short* qbase =
      Qp + (size_t)(b * SLEN + q0 + w * 16 + lq) * DMODEL;
  const int krow = t >> 2, kseg = (t & 3) * 16;

  for (int h = 0; h < NHEAD; h++) {
    __syncthreads();
    const unsigned short* kg =
        Kp + (size_t)(b * SLEN + k0 + krow) * DMODEL + h * 64 + kseg;
    *(bf16x8*)&Ks[krow * 88 + kseg]     = *(const bf16x8*)kg;
    *(bf16x8*)&Ks[krow * 88 + kseg + 8] = *(const bf16x8*)(kg + 8);
    __syncthreads();

    const bf16x8 aq0 = *(const bf16x8*)(qbase + h * 64 + quad * 8);
    const bf16x8 aq1 = *(const bf16x8*)(qbase + h * 64 + 32 + quad * 8);
    float ilr[4];
#pragma unroll
    for (int r = 0; r < 4; r++) {
      const float lv = lbuf[(b * NHEAD + h) * SLEN + q0 + w * 16 + quad * 4 + r];
      ilr[r] = (lv > 0.f) ? 1.f / lv : 0.f;
    }
#pragma unroll
    for (int ti = 0; ti < 4; ti++) {
      const bf16x8 bk0 = *(const bf16x8*)&Ks[(ti * 16 + lq) * 88 + quad * 8];
      const bf16x8 bk1 = *(const bf16x8*)&Ks[(ti * 16 + lq) * 88 + 32 + quad * 8];
      floatx4 z = (floatx4){0.f, 0.f, 0.f, 0.f};
      z = mfma16(aq0, bk0, z);
      z = mfma16(aq1, bk1, z);
#pragma unroll
      for (int r = 0; r < 4; r++)
        acc[ti][r] += mk[ti] ? __expf(z[r] * 0.125f) * ilr[r] : 0.f;
    }
  }
  const float ih = 1.f / NHEAD;
#pragma unroll
  for (int ti = 0; ti < 4; ti++)
#pragma unroll
    for (int r = 0; r < 4; r++)
      aout[(size_t)(b * SLEN + q0 + w * 16 + quad * 4 + r) * SLEN + k0 +
           ti * 16 + lq] = acc[ti][r] * ih;
}

extern "C" void kernel_launch(void* const* d_in, const int* in_sizes, int n_in,
                              void* d_out, int out_size, void* d_ws, size_t ws_size,
                              hipStream_t stream) {
  const float* q   = (const float*)d_in[0];
  const float* k   = (const float*)d_in[1];
  const float* v   = (const float*)d_in[2];
  const float* Wq  = (const float*)d_in[3];
  const float* bq  = (const float*)d_in[4];
  const float* Wk  = (const float*)d_in[5];
  const float* bk  = (const float*)d_in[6];
  const float* Wv  = (const float*)d_in[7];
  const float* bv  = (const float*)d_in[8];
  const float* Wfc = (const float*)d_in[9];
  const float* bfc = (const float*)d_in[10];
  const int* mask  = (const int*)d_in[11];

  float* out      = (float*)d_out;                 // [B,S,2D] = 33.5 MB
  float* attn_avg = out + (size_t)MROWS * DOUT;    // [B,S,S]  = 33.5 MB

  // d_out `out` region scratch (all dead before their region is written):
  // phase 1: qb/kb/vb bf16 (4M+4M+8M elems = 33.5 MB);
  // phase 2: Opart bf16 2x4M elems (16 MB) + Lpart f32 2x64K (512 KB).
  unsigned short* qb = (unsigned short*)d_out;
  unsigned short* kb = qb + (1u << 22);
  unsigned short* vb = kb + (1u << 22);
  unsigned short* Opart = (unsigned short*)d_out;
  float* Lpart = (float*)((char*)d_out + (size_t)NSPLIT * BATCH * NHEAD * SLEN * DHEAD * 2);

  // ws (bf16 elems): WqT 1M | WkT 1M | WvT 2M | WfcT 2M | Qp 4M | Kp 4M |
  // VT 4M | att 4M | lbuf f32 64K
  unsigned short* wsb  = (unsigned short*)d_ws;
  unsigned short* WqT  = wsb;
  unsigned short* WkT  = wsb + (1u << 20);
  unsigned short* WvT  = wsb + (2u << 20);
  unsigned short* WfcT = wsb + (4u << 20);
  unsigned short* Qp   = wsb + (6u << 20);
  unsigned short* Kp   = Qp + (1u << 22);
  unsigned short* VT   = Kp + (1u << 22);
  unsigned short* att  = VT + (1u << 22);
  float* lbuf = (float*)(att + (1u << 22));

  // 0) convert activations to bf16
  conv_bf16_k<<<dim3(2048), dim3(256), 0, stream>>>(q, qb, (1 << 22) / 8);
  conv_bf16_k<<<dim3(2048), dim3(256), 0, stream>>>(k, kb, (1 << 22) / 8);
  conv_bf16_k<<<dim3(4096), dim3(256), 0, stream>>>(v, vb, (1 << 23) / 8);
  // 0b) transpose + convert weights -> [N][K] bf16
  wtrans_k<<<dim3(32, 32), dim3(256), 0, stream>>>(Wq, WqT, DMODEL, DMODEL);
  wtrans_k<<<dim3(32, 32), dim3(256), 0, stream>>>(Wk, WkT, DMODEL, DMODEL);
  wtrans_k<<<dim3(32, 64), dim3(256), 0, stream>>>(Wv, WvT, 2 * DMODEL, DMODEL);
  wtrans_k<<<dim3(64, 32), dim3(256), 0, stream>>>(Wfc, WfcT, DMODEL, DOUT);
  // 1) Q+K projections fused (1024 blocks), V projection -> transposed VT
  qkproj_k<<<dim3(DMODEL / 64, MROWS / 128, 2), dim3(256), 0, stream>>>(
      qb, kb, WqT, WkT, bq, bk, Qp, Kp);
  vproj_k<<<dim3(DMODEL / 64, MROWS / 128), dim3(256), 0, stream>>>(
      vb, WvT, bv, VT);
  // 2) flash attention (m=0, k-split x2) -> Opart/Lpart in d_out arena
  flash_mfma_k<<<dim3(SLEN / 64, NHEAD * NSPLIT, BATCH), dim3(256), 0, stream>>>(
      Qp, Kp, VT, mask, Opart, Lpart);
  // 2b) combine -> att (bf16, ws) + lbuf
  combine_k<<<dim3(BATCH * NHEAD * SLEN * DHEAD / 8 / 256), dim3(256), 0, stream>>>(
      Opart, Lpart, att, lbuf);
  // 3) head-averaged attention map
  attn_avg_mfma_k<<<dim3(SLEN / 64, SLEN / 64, BATCH), dim3(256), 0, stream>>>(
      Qp, Kp, lbuf, mask, attn_avg);
  // 4) output FC (f32 out; Opart dead by now)
  fc_k<<<dim3(DOUT / 64, MROWS / 128), dim3(256), 0, stream>>>(
      att, WfcT, bfc, out);
}

// Round 5
// 373.293 us; speedup vs baseline: 8.6561x; 1.0652x over previous
//
#include <hip/hip_runtime.h>
#include <math.h>

#define BATCH   2
#define SLEN    2048
#define DMODEL  1024
#define NHEAD   16
#define DHEAD   64
#define DOUT    2048
#define MROWS   (BATCH * SLEN)   // 4096
#define NSPLIT  2
#define KSPAN   (SLEN / NSPLIT)  // 1024

typedef short bf16x8 __attribute__((ext_vector_type(8)));
typedef float floatx4 __attribute__((ext_vector_type(4)));

static __device__ __forceinline__ unsigned short f2bf(float f) {
  unsigned u = __float_as_uint(f);
  u += 0x7fff + ((u >> 16) & 1);
  return (unsigned short)(u >> 16);
}
static __device__ __forceinline__ float bf2f(unsigned short s) {
  return __uint_as_float(((unsigned)s) << 16);
}
static __device__ __forceinline__ floatx4 mfma16(bf16x8 a, bf16x8 b, floatx4 c) {
  return __builtin_amdgcn_mfma_f32_16x16x32_bf16(a, b, c, 0, 0, 0);
}
// async global->LDS, 16B per lane; LDS dest = wave-uniform base + lane*16
static __device__ __forceinline__ void gll16(const void* g, void* l) {
  __builtin_amdgcn_global_load_lds(
      (const __attribute__((address_space(1))) unsigned int*)g,
      (__attribute__((address_space(3))) unsigned int*)l, 16, 0, 0);
}

// ============ fused f32 -> bf16 convert for q,k,v (one launch) ==============
__global__ __launch_bounds__(256) void conv_all_k(
    const float* __restrict__ q, const float* __restrict__ k,
    const float* __restrict__ v, unsigned short* __restrict__ qb,
    unsigned short* __restrict__ kb, unsigned short* __restrict__ vb) {
  int i = blockIdx.x * 256 + threadIdx.x;  // vec8 units; total 2M
  const float* src;
  unsigned short* dst;
  if (i < (1 << 19)) { src = q; dst = qb; }
  else if (i < (1 << 20)) { src = k; dst = kb; i -= 1 << 19; }
  else { src = v; dst = vb; i -= 1 << 20; }
  const float4 a = ((const float4*)src)[i * 2];
  const float4 b = ((const float4*)src)[i * 2 + 1];
  ushort4 u0, u1;
  u0.x = f2bf(a.x); u0.y = f2bf(a.y); u0.z = f2bf(a.z); u0.w = f2bf(a.w);
  u1.x = f2bf(b.x); u1.y = f2bf(b.y); u1.z = f2bf(b.z); u1.w = f2bf(b.w);
  ((ushort4*)dst)[i * 2] = u0;
  ((ushort4*)dst)[i * 2 + 1] = u1;
}

// ==== fused W[K][N] f32 -> WT[N][K] bf16 for all four weights (one launch) ==
__global__ __launch_bounds__(256) void wtrans_all_k(
    const float* __restrict__ Wq, const float* __restrict__ Wk,
    const float* __restrict__ Wv, const float* __restrict__ Wfc,
    unsigned short* __restrict__ WqT, unsigned short* __restrict__ WkT,
    unsigned short* __restrict__ WvT, unsigned short* __restrict__ WfcT) {
  __shared__ float T[32][33];
  int id = blockIdx.x;
  const float* W;
  unsigned short* WT;
  int K, N;
  if (id < 1024)      { W = Wq;  WT = WqT;  K = 1024; N = 1024; }
  else if (id < 2048) { W = Wk;  WT = WkT;  K = 1024; N = 1024; id -= 1024; }
  else if (id < 4096) { W = Wv;  WT = WvT;  K = 2048; N = 1024; id -= 2048; }
  else                { W = Wfc; WT = WfcT; K = 1024; N = 2048; id -= 4096; }
  const int ntn = N / 32;
  const int n0 = (id % ntn) * 32, k0 = (id / ntn) * 32;
  const int t = threadIdx.x;
  {
    const int r = t >> 3, c4 = (t & 7) * 4;
    const float4 w = *(const float4*)(W + (size_t)(k0 + r) * N + n0 + c4);
    T[r][c4 + 0] = w.x; T[r][c4 + 1] = w.y; T[r][c4 + 2] = w.z; T[r][c4 + 3] = w.w;
  }
  __syncthreads();
  {
    const int n = t >> 3, k4 = (t & 7) * 4;
    ushort4 u;
    u.x = f2bf(T[k4 + 0][n]); u.y = f2bf(T[k4 + 1][n]);
    u.z = f2bf(T[k4 + 2][n]); u.w = f2bf(T[k4 + 3][n]);
    *(ushort4*)(WT + (size_t)(n0 + n) * K + k0 + k4) = u;
  }
}

// ====== MFMA GEMM body: C = A[M][K] x BT[N][K]^T + bias. 128x64 tile, BK=64,
// 256 thr = 4 waves. global_load_lds into XOR-swizzled LDS.
// MODE: 0 = bf16 row-major, 1 = f32 row-major, 2 = bf16 transposed C^T[N][M].
template <int MODE>
static __device__ __forceinline__ void gemm_body(
    const unsigned short* __restrict__ A, const unsigned short* __restrict__ BT,
    const float* __restrict__ bias, void* __restrict__ C, int M, int K, int N,
    int row0, int col0) {
  __shared__ unsigned short As[128 * 64];
  __shared__ unsigned short Bs[64 * 64];
  const int t = threadIdx.x;
  const int w = t >> 6, l = t & 63, quad = l >> 4, lq = l & 15;
  const int wm = (w >> 1) * 64, wn = (w & 1) * 32;

  const unsigned short* aS[4];
#pragma unroll
  for (int jj = 0; jj < 4; jj++) {
    const int m = (w * 4 + jj) * 8 + (l >> 3);
    aS[jj] = A + (size_t)(row0 + m) * K + (((l & 7) ^ (m & 7)) << 3);
  }
  const unsigned short* bS[2];
#pragma unroll
  for (int jj = 0; jj < 2; jj++) {
    const int n = (w * 2 + jj) * 8 + (l >> 3);
    bS[jj] = BT + (size_t)(col0 + n) * K + (((l & 7) ^ (n & 7)) << 3);
  }

  floatx4 acc[4][2];
#pragma unroll
  for (int i = 0; i < 4; i++)
#pragma unroll
    for (int j = 0; j < 2; j++) acc[i][j] = (floatx4){0.f, 0.f, 0.f, 0.f};

  for (int kt = 0; kt < K; kt += 64) {
#pragma unroll
    for (int jj = 0; jj < 4; jj++)
      gll16(aS[jj] + kt, As + (w * 4 + jj) * 512);
#pragma unroll
    for (int jj = 0; jj < 2; jj++)
      gll16(bS[jj] + kt, Bs + (w * 2 + jj) * 512);
    __syncthreads();

    bf16x8 af[4][2], bfr[2][2];
#pragma unroll
    for (int ti = 0; ti < 4; ti++) {
      const int m = wm + ti * 16 + lq;
#pragma unroll
      for (int h = 0; h < 2; h++)
        af[ti][h] = *(const bf16x8*)(As + m * 64 + (((h * 4 + quad) ^ (m & 7)) << 3));
    }
#pragma unroll
    for (int tj = 0; tj < 2; tj++) {
      const int n = wn + tj * 16 + lq;
#pragma unroll
      for (int h = 0; h < 2; h++)
        bfr[tj][h] = *(const bf16x8*)(Bs + n * 64 + (((h * 4 + quad) ^ (n & 7)) << 3));
    }
#pragma unroll
    for (int ti = 0; ti < 4; ti++)
#pragma unroll
      for (int tj = 0; tj < 2; tj++) {
        acc[ti][tj] = mfma16(af[ti][0], bfr[tj][0], acc[ti][tj]);
        acc[ti][tj] = mfma16(af[ti][1], bfr[tj][1], acc[ti][tj]);
      }
    __syncthreads();
  }

#pragma unroll
  for (int tj = 0; tj < 2; tj++) {
    const int col = col0 + wn + tj * 16 + lq;
    const float bv = bias[col];
    if (MODE == 2) {
#pragma unroll
      for (int ti = 0; ti < 4; ti++) {
        ushort4 u;
        u.x = f2bf(acc[ti][tj][0] + bv);
        u.y = f2bf(acc[ti][tj][1] + bv);
        u.z = f2bf(acc[ti][tj][2] + bv);
        u.w = f2bf(acc[ti][tj][3] + bv);
        *(ushort4*)((unsigned short*)C + (size_t)col * M + row0 + wm + ti * 16 +
                    quad * 4) = u;
      }
    } else {
#pragma unroll
      for (int ti = 0; ti < 4; ti++)
#pragma unroll
        for (int r = 0; r < 4; r++) {
          const int row = row0 + wm + ti * 16 + quad * 4 + r;
          const float vv = acc[ti][tj][r] + bv;
          if (MODE == 1)
            ((float*)C)[(size_t)row * N + col] = vv;
          else
            ((unsigned short*)C)[(size_t)row * N + col] = f2bf(vv);
        }
    }
  }
}

__global__ __launch_bounds__(256) void qkproj_k(
    const unsigned short* qb, const unsigned short* kb,
    const unsigned short* WqT, const unsigned short* WkT,
    const float* bq, const float* bk,
    unsigned short* Qp, unsigned short* Kp) {
  const int z = blockIdx.z;
  gemm_body<0>(z ? kb : qb, z ? WkT : WqT, z ? bk : bq, z ? Kp : Qp,
               MROWS, DMODEL, DMODEL, blockIdx.y * 128, blockIdx.x * 64);
}
__global__ __launch_bounds__(256) void vproj_k(
    const unsigned short* vb, const unsigned short* WvT, const float* bv,
    unsigned short* VT) {
  gemm_body<2>(vb, WvT, bv, VT, MROWS, 2 * DMODEL, DMODEL,
               blockIdx.y * 128, blockIdx.x * 64);
}
__global__ __launch_bounds__(256) void fc_k(
    const unsigned short* att, const unsigned short* WfcT, const float* bfc,
    float* out) {
  gemm_body<1>(att, WfcT, bfc, out, MROWS, DMODEL, DOUT,
               blockIdx.y * 128, blockIdx.x * 64);
}

// ============== Flash attention (m=0), S^T = K·Q^T formulation ==============
// Block = (b, h, split, q-tile64), 4 waves, wave owns 16 q rows (q = lq).
// S^T C-layout gives P^T rows kk=quad*4+r, col q=lq -> packed b64 LDS writes.
__global__ __launch_bounds__(256) void flash_mfma_k(
    const unsigned short* __restrict__ Qp, const unsigned short* __restrict__ Kp,
    const unsigned short* __restrict__ VT, const int* __restrict__ mask,
    unsigned short* __restrict__ Opart, float* __restrict__ Lpart) {
  __shared__ unsigned short Ks[64 * 64];   // [kk][d], XOR-swizzled 16B chunks
  __shared__ unsigned short Vs[64 * 64];   // [d][kk], XOR-swizzled
  __shared__ unsigned short Ps[4][16 * 68];// per-wave [q][kk], stride 68
  const int t = threadIdx.x;
  const int w = t >> 6, l = t & 63, quad = l >> 4, lq = l & 15;
  const int q0 = blockIdx.x * 64;
  const int h = blockIdx.y >> 1, split = blockIdx.y & 1;
  const int b = blockIdx.z;

  const unsigned short* qptr =
      Qp + (size_t)(b * SLEN + q0 + w * 16 + lq) * DMODEL + h * 64;
  const bf16x8 aq0 = *(const bf16x8*)(qptr + quad * 8);
  const bf16x8 aq1 = *(const bf16x8*)(qptr + 32 + quad * 8);

  // staging source offsets (lane-constant)
  int krow[2], kchunk[2];
#pragma unroll
  for (int jj = 0; jj < 2; jj++) {
    krow[jj] = (w * 2 + jj) * 8 + (l >> 3);
    kchunk[jj] = (l & 7) ^ (krow[jj] & 7);
  }
  const unsigned short* Kbase = Kp + (size_t)b * SLEN * DMODEL + h * 64;
  const unsigned short* Vbase = VT + (size_t)h * 64 * MROWS + b * SLEN;

  floatx4 acc_o[4];
#pragma unroll
  for (int dj = 0; dj < 4; dj++) acc_o[dj] = (floatx4){0.f, 0.f, 0.f, 0.f};
  float lsum = 0.f;
  unsigned short* PsW = &Ps[w][0];

  for (int k0 = split * KSPAN; k0 < split * KSPAN + KSPAN; k0 += 64) {
    __syncthreads();
#pragma unroll
    for (int jj = 0; jj < 2; jj++) {
      const int inst = w * 2 + jj;
      gll16(Kbase + (size_t)(k0 + krow[jj]) * DMODEL + kchunk[jj] * 8,
            Ks + inst * 512);
      gll16(Vbase + (size_t)krow[jj] * MROWS + k0 + kchunk[jj] * 8,
            Vs + inst * 512);
    }
    __syncthreads();

    // S^T tiles: rows kk = ti*16 + quad*4 + r, col q = lq
#pragma unroll
    for (int ti = 0; ti < 4; ti++) {
      const int kk = ti * 16 + lq;
      const bf16x8 bk0 = *(const bf16x8*)(Ks + kk * 64 + ((quad ^ (kk & 7)) << 3));
      const bf16x8 bk1 =
          *(const bf16x8*)(Ks + kk * 64 + (((4 + quad) ^ (kk & 7)) << 3));
      floatx4 z = (floatx4){0.f, 0.f, 0.f, 0.f};
      z = mfma16(bk0, aq0, z);
      z = mfma16(bk1, aq1, z);
      const int4 m4 = *(const int4*)(mask + b * SLEN + k0 + ti * 16 + quad * 4);
      const int mv[4] = {m4.x, m4.y, m4.z, m4.w};
      float e[4];
#pragma unroll
      for (int r = 0; r < 4; r++) {
        float ev = __expf(z[r] * 0.125f);
        ev = mv[r] ? ev : 0.f;
        e[r] = ev;
        lsum += ev;
      }
      ushort4 u;
      u.x = f2bf(e[0]); u.y = f2bf(e[1]); u.z = f2bf(e[2]); u.w = f2bf(e[3]);
      *(ushort4*)(PsW + lq * 68 + ti * 16 + quad * 4) = u;  // conflict-free b64
    }
    __asm__ __volatile__("" ::: "memory");  // order Ps writes before reads
    const bf16x8 ap0 = *(const bf16x8*)(PsW + lq * 68 + quad * 8);
    const bf16x8 ap1 = *(const bf16x8*)(PsW + lq * 68 + 32 + quad * 8);
#pragma unroll
    for (int dj = 0; dj < 4; dj++) {
      const int d = dj * 16 + lq;
      const bf16x8 bv0 = *(const bf16x8*)(Vs + d * 64 + ((quad ^ (d & 7)) << 3));
      const bf16x8 bv1 =
          *(const bf16x8*)(Vs + d * 64 + (((4 + quad) ^ (d & 7)) << 3));
      acc_o[dj] = mfma16(ap0, bv0, acc_o[dj]);
      acc_o[dj] = mfma16(ap1, bv1, acc_o[dj]);
    }
  }

  // l[q=lq]: sum in-lane parts across the 4 quad groups
  lsum += __shfl_xor(lsum, 16);
  lsum += __shfl_xor(lsum, 32);

  const size_t obase =
      (((size_t)split * BATCH + b) * NHEAD + h) * SLEN + q0 + w * 16;
#pragma unroll
  for (int dj = 0; dj < 4; dj++)
#pragma unroll
    for (int r = 0; r < 4; r++)
      Opart[(obase + quad * 4 + r) * DHEAD + dj * 16 + lq] = f2bf(acc_o[dj][r]);
  if (quad == 0) Lpart[obase + lq] = lsum;
}

// ======= combine split partials: att = (O0+O1)/(l0+l1), lbuf = l0+l1 ========
__global__ __launch_bounds__(256) void combine_k(
    const unsigned short* __restrict__ Opart, const float* __restrict__ Lpart,
    unsigned short* __restrict__ att, float* __restrict__ lbuf) {
  const int gid = blockIdx.x * 256 + threadIdx.x;
  const int row = gid >> 3;
  const int d8 = (gid & 7) * 8;
  const float l0 = Lpart[row];
  const float l1 = Lpart[(size_t)BATCH * NHEAD * SLEN + row];
  const float lt = l0 + l1;
  const float il = (lt > 0.f) ? 1.f / lt : 0.f;
  const bf16x8 o0 = *(const bf16x8*)(Opart + (size_t)row * DHEAD + d8);
  const bf16x8 o1 = *(const bf16x8*)(Opart + (size_t)(BATCH * NHEAD * SLEN) * DHEAD +
                                     (size_t)row * DHEAD + d8);
  const int b = row >> 15, hh = (row >> 11) & 15, q = row & 2047;
  unsigned short* dst = att + (size_t)(b * SLEN + q) * DMODEL + hh * 64 + d8;
  ushort4 u0, u1;
  float vv[8];
#pragma unroll
  for (int j = 0; j < 8; j++)
    vv[j] = (bf2f((unsigned short)o0[j]) + bf2f((unsigned short)o1[j])) * il;
  u0.x = f2bf(vv[0]); u0.y = f2bf(vv[1]); u0.z = f2bf(vv[2]); u0.w = f2bf(vv[3]);
  u1.x = f2bf(vv[4]); u1.y = f2bf(vv[5]); u1.z = f2bf(vv[6]); u1.w = f2bf(vv[7]);
  ((ushort4*)dst)[0] = u0;
  ((ushort4*)dst)[1] = u1;
  if ((gid & 7) == 0) lbuf[row] = lt;
}

// ======= attn_avg[b,q,k] = (1/H) sum_h exp(s_h(q,k)) / l[b,h,q]  (m=0) ======
__global__ __launch_bounds__(256) void attn_avg_mfma_k(
    const unsigned short* __restrict__ Qp, const unsigned short* __restrict__ Kp,
    const float* __restrict__ lbuf, const int* __restrict__ mask,
    float* __restrict__ aout) {
  __shared__ unsigned short Ks[64 * 64];  // XOR-swizzled
  const int t = threadIdx.x;
  const int w = t >> 6, l = t & 63, quad = l >> 4, lq = l & 15;
  const int k0 = blockIdx.x * 64, q0 = blockIdx.y * 64, b = blockIdx.z;

  floatx4 acc[4];
#pragma unroll
  for (int ti = 0; ti < 4; ti++) acc[ti] = (floatx4){0.f, 0.f, 0.f, 0.f};
  int mk[4];
#pragma unroll
  for (int ti = 0; ti < 4; ti++) mk[ti] = mask[b * SLEN + k0 + ti * 16 + lq];

  int krow[2], kchunk[2];
#pragma unroll
  for (int jj = 0; jj < 2; jj++) {
    krow[jj] = (w * 2 + jj) * 8 + (l >> 3);
    kchunk[jj] = (l & 7) ^ (krow[jj] & 7);
  }
  const unsigned short* Kbase = Kp + (size_t)(b * SLEN + k0) * DMODEL;
  const unsigned short* qbase =
      Qp + (size_t)(b * SLEN + q0 + w * 16 + lq) * DMODEL;

  for (int h = 0; h < NHEAD; h++) {
    __syncthreads();
#pragma unroll
    for (int jj = 0; jj < 2; jj++)
      gll16(Kbase + (size_t)krow[jj] * DMODEL + h * 64 + kchunk[jj] * 8,
            Ks + (w * 2 + jj) * 512);
    __syncthreads();

    const bf16x8 aq0 = *(const bf16x8*)(qbase + h * 64 + quad * 8);
    const bf16x8 aq1 = *(const bf16x8*)(qbase + h * 64 + 32 + quad * 8);
    float ilr[4];
#pragma unroll
    for (int r = 0; r < 4; r++) {
      const float lv = lbuf[(b * NHEAD + h) * SLEN + q0 + w * 16 + quad * 4 + r];
      ilr[r] = (lv > 0.f) ? 1.f / lv : 0.f;
    }
#pragma unroll
    for (int ti = 0; ti < 4; ti++) {
      const int kk = ti * 16 + lq;
      const bf16x8 bk0 = *(const bf16x8*)(Ks + kk * 64 + ((quad ^ (kk & 7)) << 3));
      const bf16x8 bk1 =
          *(const bf16x8*)(Ks + kk * 64 + (((4 + quad) ^ (kk & 7)) << 3));
      floatx4 z = (floatx4){0.f, 0.f, 0.f, 0.f};
      z = mfma16(aq0, bk0, z);
      z = mfma16(aq1, bk1, z);
#pragma unroll
      for (int r = 0; r < 4; r++)
        acc[ti][r] += mk[ti] ? __expf(z[r] * 0.125f) * ilr[r] : 0.f;
    }
  }
  const float ih = 1.f / NHEAD;
#pragma unroll
  for (int ti = 0; ti < 4; ti++)
#pragma unroll
    for (int r = 0; r < 4; r++)
      aout[(size_t)(b * SLEN + q0 + w * 16 + quad * 4 + r) * SLEN + k0 +
           ti * 16 + lq] = acc[ti][r] * ih;
}

extern "C" void kernel_launch(void* const* d_in, const int* in_sizes, int n_in,
                              void* d_out, int out_size, void* d_ws, size_t ws_size,
                              hipStream_t stream) {
  const float* q   = (const float*)d_in[0];
  const float* k   = (const float*)d_in[1];
  const float* v   = (const float*)d_in[2];
  const float* Wq  = (const float*)d_in[3];
  const float* bq  = (const float*)d_in[4];
  const float* Wk  = (const float*)d_in[5];
  const float* bk  = (const float*)d_in[6];
  const float* Wv  = (const float*)d_in[7];
  const float* bv  = (const float*)d_in[8];
  const float* Wfc = (const float*)d_in[9];
  const float* bfc = (const float*)d_in[10];
  const int* mask  = (const int*)d_in[11];

  float* out      = (float*)d_out;                 // [B,S,2D] = 33.5 MB
  float* attn_avg = out + (size_t)MROWS * DOUT;    // [B,S,S]  = 33.5 MB

  // d_out `out` region scratch (dead before the FC writes it):
  // phase 1: qb/kb/vb bf16 (33.5 MB); phase 2: Opart bf16 16 MB + Lpart 512 KB.
  unsigned short* qb = (unsigned short*)d_out;
  unsigned short* kb = qb + (1u << 22);
  unsigned short* vb = kb + (1u << 22);
  unsigned short* Opart = (unsigned short*)d_out;
  float* Lpart = (float*)((char*)d_out + (size_t)NSPLIT * BATCH * NHEAD * SLEN * DHEAD * 2);

  // ws (bf16 elems): WqT 1M | WkT 1M | WvT 2M | WfcT 2M | Qp 4M | Kp 4M |
  // VT 4M | att 4M | lbuf f32 64K
  unsigned short* wsb  = (unsigned short*)d_ws;
  unsigned short* WqT  = wsb;
  unsigned short* WkT  = wsb + (1u << 20);
  unsigned short* WvT  = wsb + (2u << 20);
  unsigned short* WfcT = wsb + (4u << 20);
  unsigned short* Qp   = wsb + (6u << 20);
  unsigned short* Kp   = Qp + (1u << 22);
  unsigned short* VT   = Kp + (1u << 22);
  unsigned short* att  = VT + (1u << 22);
  float* lbuf = (float*)(att + (1u << 22));

  // 0) converts + weight transposes (fused launches)
  conv_all_k<<<dim3(8192), dim3(256), 0, stream>>>(q, k, v, qb, kb, vb);
  wtrans_all_k<<<dim3(6144), dim3(256), 0, stream>>>(Wq, Wk, Wv, Wfc,
                                                     WqT, WkT, WvT, WfcT);
  // 1) Q+K projections fused; V projection -> transposed VT
  qkproj_k<<<dim3(DMODEL / 64, MROWS / 128, 2), dim3(256), 0, stream>>>(
      qb, kb, WqT, WkT, bq, bk, Qp, Kp);
  vproj_k<<<dim3(DMODEL / 64, MROWS / 128), dim3(256), 0, stream>>>(
      vb, WvT, bv, VT);
  // 2) flash attention (S^T form, k-split x2) -> Opart/Lpart
  flash_mfma_k<<<dim3(SLEN / 64, NHEAD * NSPLIT, BATCH), dim3(256), 0, stream>>>(
      Qp, Kp, VT, mask, Opart, Lpart);
  // 2b) combine -> att (bf16) + lbuf
  combine_k<<<dim3(BATCH * NHEAD * SLEN * DHEAD / 8 / 256), dim3(256), 0, stream>>>(
      Opart, Lpart, att, lbuf);
  // 3) head-averaged attention map
  attn_avg_mfma_k<<<dim3(SLEN / 64, SLEN / 64, BATCH), dim3(256), 0, stream>>>(
      Qp, Kp, lbuf, mask, attn_avg);
  // 4) output FC
  fc_k<<<dim3(DOUT / 64, MROWS / 128), dim3(256), 0, stream>>>(
      att, WfcT, bfc, out);
}

// Round 6
// 367.176 us; speedup vs baseline: 8.8003x; 1.0167x over previous
//
#include <hip/hip_runtime.h>
#include <math.h>

#define BATCH   2
#define SLEN    2048
#define DMODEL  1024
#define NHEAD   16
#define DHEAD   64
#define DOUT    2048
#define MROWS   (BATCH * SLEN)   // 4096
#define NSPLIT  2
#define KSPAN   (SLEN / NSPLIT)  // 1024

typedef short bf16x8 __attribute__((ext_vector_type(8)));
typedef float floatx4 __attribute__((ext_vector_type(4)));

static __device__ __forceinline__ unsigned short f2bf(float f) {
  unsigned u = __float_as_uint(f);
  u += 0x7fff + ((u >> 16) & 1);
  return (unsigned short)(u >> 16);
}
static __device__ __forceinline__ float bf2f(unsigned short s) {
  return __uint_as_float(((unsigned)s) << 16);
}
// pack two f32 -> two bf16 (RNE). gfx950 has V_CVT_PK_BF16_F32 (1 inst).
static __device__ __forceinline__ unsigned int pk_bf16(float a, float b) {
#if defined(__gfx950__) && __has_builtin(__builtin_amdgcn_cvt_pk_bf16_f32)
  typedef __bf16 bf2_t __attribute__((ext_vector_type(2)));
  bf2_t r = __builtin_amdgcn_cvt_pk_bf16_f32(a, b);
  return __builtin_bit_cast(unsigned int, r);
#else
  return ((unsigned)f2bf(b) << 16) | f2bf(a);
#endif
}
static __device__ __forceinline__ floatx4 mfma16(bf16x8 a, bf16x8 b, floatx4 c) {
  return __builtin_amdgcn_mfma_f32_16x16x32_bf16(a, b, c, 0, 0, 0);
}
// async global->LDS, 16B per lane; LDS dest = wave-uniform base + lane*16
static __device__ __forceinline__ void gll16(const void* g, void* l) {
  __builtin_amdgcn_global_load_lds(
      (const __attribute__((address_space(1))) unsigned int*)g,
      (__attribute__((address_space(3))) unsigned int*)l, 16, 0, 0);
}

// ============ fused f32 -> bf16 convert for q,k,v (one launch) ==============
__global__ __launch_bounds__(256) void conv_all_k(
    const float* __restrict__ q, const float* __restrict__ k,
    const float* __restrict__ v, unsigned short* __restrict__ qb,
    unsigned short* __restrict__ kb, unsigned short* __restrict__ vb) {
  int i = blockIdx.x * 256 + threadIdx.x;  // vec8 units; total 2M
  const float* src;
  unsigned short* dst;
  if (i < (1 << 19)) { src = q; dst = qb; }
  else if (i < (1 << 20)) { src = k; dst = kb; i -= 1 << 19; }
  else { src = v; dst = vb; i -= 1 << 20; }
  const float4 a = ((const float4*)src)[i * 2];
  const float4 b = ((const float4*)src)[i * 2 + 1];
  uint4 u;
  u.x = pk_bf16(a.x, a.y);
  u.y = pk_bf16(a.z, a.w);
  u.z = pk_bf16(b.x, b.y);
  u.w = pk_bf16(b.z, b.w);
  ((uint4*)dst)[i] = u;
}

// ==== fused W[K][N] f32 -> WT[N][K] bf16 for all four weights (one launch) ==
__global__ __launch_bounds__(256) void wtrans_all_k(
    const float* __restrict__ Wq, const float* __restrict__ Wk,
    const float* __restrict__ Wv, const float* __restrict__ Wfc,
    unsigned short* __restrict__ WqT, unsigned short* __restrict__ WkT,
    unsigned short* __restrict__ WvT, unsigned short* __restrict__ WfcT) {
  __shared__ float T[32][33];
  int id = blockIdx.x;
  const float* W;
  unsigned short* WT;
  int K, N;
  if (id < 1024)      { W = Wq;  WT = WqT;  K = 1024; N = 1024; }
  else if (id < 2048) { W = Wk;  WT = WkT;  K = 1024; N = 1024; id -= 1024; }
  else if (id < 4096) { W = Wv;  WT = WvT;  K = 2048; N = 1024; id -= 2048; }
  else                { W = Wfc; WT = WfcT; K = 1024; N = 2048; id -= 4096; }
  const int ntn = N / 32;
  const int n0 = (id % ntn) * 32, k0 = (id / ntn) * 32;
  const int t = threadIdx.x;
  {
    const int r = t >> 3, c4 = (t & 7) * 4;
    const float4 w = *(const float4*)(W + (size_t)(k0 + r) * N + n0 + c4);
    T[r][c4 + 0] = w.x; T[r][c4 + 1] = w.y; T[r][c4 + 2] = w.z; T[r][c4 + 3] = w.w;
  }
  __syncthreads();
  {
    const int n = t >> 3, k4 = (t & 7) * 4;
    uint2 u;
    u.x = pk_bf16(T[k4 + 0][n], T[k4 + 1][n]);
    u.y = pk_bf16(T[k4 + 2][n], T[k4 + 3][n]);
    *(uint2*)(WT + (size_t)(n0 + n) * K + k0 + k4) = u;
  }
}

// ====== MFMA GEMM body: C = A[M][K] x BT[N][K]^T + bias. 128x64 tile, BK=64,
// 256 thr = 4 waves. global_load_lds into XOR-swizzled LDS.
// MODE: 0 = bf16 row-major, 1 = f32 row-major, 2 = bf16 transposed C^T[N][M].
template <int MODE>
static __device__ __forceinline__ void gemm_body(
    const unsigned short* __restrict__ A, const unsigned short* __restrict__ BT,
    const float* __restrict__ bias, void* __restrict__ C, int M, int K, int N,
    int row0, int col0) {
  __shared__ unsigned short As[128 * 64];
  __shared__ unsigned short Bs[64 * 64];
  const int t = threadIdx.x;
  const int w = t >> 6, l = t & 63, quad = l >> 4, lq = l & 15;
  const int wm = (w >> 1) * 64, wn = (w & 1) * 32;

  const unsigned short* aS[4];
#pragma unroll
  for (int jj = 0; jj < 4; jj++) {
    const int m = (w * 4 + jj) * 8 + (l >> 3);
    aS[jj] = A + (size_t)(row0 + m) * K + (((l & 7) ^ (m & 7)) << 3);
  }
  const unsigned short* bS[2];
#pragma unroll
  for (int jj = 0; jj < 2; jj++) {
    const int n = (w * 2 + jj) * 8 + (l >> 3);
    bS[jj] = BT + (size_t)(col0 + n) * K + (((l & 7) ^ (n & 7)) << 3);
  }

  floatx4 acc[4][2];
#pragma unroll
  for (int i = 0; i < 4; i++)
#pragma unroll
    for (int j = 0; j < 2; j++) acc[i][j] = (floatx4){0.f, 0.f, 0.f, 0.f};

  for (int kt = 0; kt < K; kt += 64) {
#pragma unroll
    for (int jj = 0; jj < 4; jj++)
      gll16(aS[jj] + kt, As + (w * 4 + jj) * 512);
#pragma unroll
    for (int jj = 0; jj < 2; jj++)
      gll16(bS[jj] + kt, Bs + (w * 2 + jj) * 512);
    __syncthreads();

    bf16x8 af[4][2], bfr[2][2];
#pragma unroll
    for (int ti = 0; ti < 4; ti++) {
      const int m = wm + ti * 16 + lq;
#pragma unroll
      for (int h = 0; h < 2; h++)
        af[ti][h] = *(const bf16x8*)(As + m * 64 + (((h * 4 + quad) ^ (m & 7)) << 3));
    }
#pragma unroll
    for (int tj = 0; tj < 2; tj++) {
      const int n = wn + tj * 16 + lq;
#pragma unroll
      for (int h = 0; h < 2; h++)
        bfr[tj][h] = *(const bf16x8*)(Bs + n * 64 + (((h * 4 + quad) ^ (n & 7)) << 3));
    }
#pragma unroll
    for (int ti = 0; ti < 4; ti++)
#pragma unroll
      for (int tj = 0; tj < 2; tj++) {
        acc[ti][tj] = mfma16(af[ti][0], bfr[tj][0], acc[ti][tj]);
        acc[ti][tj] = mfma16(af[ti][1], bfr[tj][1], acc[ti][tj]);
      }
    __syncthreads();
  }

#pragma unroll
  for (int tj = 0; tj < 2; tj++) {
    const int col = col0 + wn + tj * 16 + lq;
    const float bv = bias[col];
    if (MODE == 2) {
#pragma unroll
      for (int ti = 0; ti < 4; ti++) {
        uint2 u;
        u.x = pk_bf16(acc[ti][tj][0] + bv, acc[ti][tj][1] + bv);
        u.y = pk_bf16(acc[ti][tj][2] + bv, acc[ti][tj][3] + bv);
        *(uint2*)((unsigned short*)C + (size_t)col * M + row0 + wm + ti * 16 +
                  quad * 4) = u;
      }
    } else {
#pragma unroll
      for (int ti = 0; ti < 4; ti++)
#pragma unroll
        for (int r = 0; r < 4; r++) {
          const int row = row0 + wm + ti * 16 + quad * 4 + r;
          const float vv = acc[ti][tj][r] + bv;
          if (MODE == 1)
            ((float*)C)[(size_t)row * N + col] = vv;
          else
            ((unsigned short*)C)[(size_t)row * N + col] = f2bf(vv);
        }
    }
  }
}

// all three projections in one launch (blockIdx.z selects; block-uniform)
__global__ __launch_bounds__(256) void proj_k(
    const unsigned short* qb, const unsigned short* kb, const unsigned short* vb,
    const unsigned short* WqT, const unsigned short* WkT,
    const unsigned short* WvT, const float* bq, const float* bk,
    const float* bv, unsigned short* Qp, unsigned short* Kp,
    unsigned short* VT) {
  const int z = blockIdx.z;
  if (z == 2)
    gemm_body<2>(vb, WvT, bv, VT, MROWS, 2 * DMODEL, DMODEL,
                 blockIdx.y * 128, blockIdx.x * 64);
  else if (z == 1)
    gemm_body<0>(kb, WkT, bk, Kp, MROWS, DMODEL, DMODEL,
                 blockIdx.y * 128, blockIdx.x * 64);
  else
    gemm_body<0>(qb, WqT, bq, Qp, MROWS, DMODEL, DMODEL,
                 blockIdx.y * 128, blockIdx.x * 64);
}
__global__ __launch_bounds__(256) void fc_k(
    const unsigned short* att, const unsigned short* WfcT, const float* bfc,
    float* out) {
  gemm_body<1>(att, WfcT, bfc, out, MROWS, DMODEL, DOUT,
               blockIdx.y * 128, blockIdx.x * 64);
}

// ============== Flash attention (m=0), S^T = K·Q^T formulation ==============
// Block = (b, h, split, q-tile64), 4 waves, wave owns 16 q rows (q = lq).
// Mask folded as additive bias (LDS, precomputed once per block).
__global__ __launch_bounds__(256) void flash_mfma_k(
    const unsigned short* __restrict__ Qp, const unsigned short* __restrict__ Kp,
    const unsigned short* __restrict__ VT, const int* __restrict__ mask,
    unsigned short* __restrict__ Opart, float* __restrict__ Lpart) {
  __shared__ unsigned short Ks[64 * 64];    // [kk][d], XOR-swizzled 16B chunks
  __shared__ unsigned short Vs[64 * 64];    // [d][kk], XOR-swizzled
  __shared__ unsigned short Ps[4][16 * 68]; // per-wave [q][kk], stride 68
  __shared__ float biasL[KSPAN];            // 4 KB: mask ? 0 : -inf
  const int t = threadIdx.x;
  const int w = t >> 6, l = t & 63, quad = l >> 4, lq = l & 15;
  const int q0 = blockIdx.x * 64;
  const int h = blockIdx.y >> 1, split = blockIdx.y & 1;
  const int b = blockIdx.z;

  for (int i = t; i < KSPAN; i += 256)
    biasL[i] = mask[b * SLEN + split * KSPAN + i] ? 0.f : -INFINITY;

  const unsigned short* qptr =
      Qp + (size_t)(b * SLEN + q0 + w * 16 + lq) * DMODEL + h * 64;
  const bf16x8 aq0 = *(const bf16x8*)(qptr + quad * 8);
  const bf16x8 aq1 = *(const bf16x8*)(qptr + 32 + quad * 8);

  int krow[2], kchunk[2];
#pragma unroll
  for (int jj = 0; jj < 2; jj++) {
    krow[jj] = (w * 2 + jj) * 8 + (l >> 3);
    kchunk[jj] = (l & 7) ^ (krow[jj] & 7);
  }
  const unsigned short* Kbase = Kp + (size_t)b * SLEN * DMODEL + h * 64;
  const unsigned short* Vbase = VT + (size_t)h * 64 * MROWS + b * SLEN;

  floatx4 acc_o[4];
#pragma unroll
  for (int dj = 0; dj < 4; dj++) acc_o[dj] = (floatx4){0.f, 0.f, 0.f, 0.f};
  float lsum = 0.f;
  unsigned short* PsW = &Ps[w][0];

  for (int k0s = 0; k0s < KSPAN; k0s += 64) {
    const int k0 = split * KSPAN + k0s;
    __syncthreads();  // also covers biasL visibility on first iter
#pragma unroll
    for (int jj = 0; jj < 2; jj++) {
      const int inst = w * 2 + jj;
      gll16(Kbase + (size_t)(k0 + krow[jj]) * DMODEL + kchunk[jj] * 8,
            Ks + inst * 512);
      gll16(Vbase + (size_t)krow[jj] * MROWS + k0 + kchunk[jj] * 8,
            Vs + inst * 512);
    }
    __syncthreads();

    // S^T tiles: rows kk = ti*16 + quad*4 + r, col q = lq
#pragma unroll
    for (int ti = 0; ti < 4; ti++) {
      const int kk = ti * 16 + lq;
      const bf16x8 bk0 = *(const bf16x8*)(Ks + kk * 64 + ((quad ^ (kk & 7)) << 3));
      const bf16x8 bk1 =
          *(const bf16x8*)(Ks + kk * 64 + (((4 + quad) ^ (kk & 7)) << 3));
      floatx4 z = (floatx4){0.f, 0.f, 0.f, 0.f};
      z = mfma16(bk0, aq0, z);
      z = mfma16(bk1, aq1, z);
      const float4 bb = *(const float4*)&biasL[k0s + ti * 16 + quad * 4];
      const float e0 = __expf(fmaf(z[0], 0.125f, bb.x));
      const float e1 = __expf(fmaf(z[1], 0.125f, bb.y));
      const float e2 = __expf(fmaf(z[2], 0.125f, bb.z));
      const float e3 = __expf(fmaf(z[3], 0.125f, bb.w));
      lsum += (e0 + e1) + (e2 + e3);
      uint2 pk;
      pk.x = pk_bf16(e0, e1);
      pk.y = pk_bf16(e2, e3);
      *(uint2*)(PsW + lq * 68 + ti * 16 + quad * 4) = pk;  // conflict-free b64
    }
    __asm__ __volatile__("" ::: "memory");  // order Ps writes before reads
    const bf16x8 ap0 = *(const bf16x8*)(PsW + lq * 68 + quad * 8);
    const bf16x8 ap1 = *(const bf16x8*)(PsW + lq * 68 + 32 + quad * 8);
#pragma unroll
    for (int dj = 0; dj < 4; dj++) {
      const int d = dj * 16 + lq;
      const bf16x8 bv0 = *(const bf16x8*)(Vs + d * 64 + ((quad ^ (d & 7)) << 3));
      const bf16x8 bv1 =
          *(const bf16x8*)(Vs + d * 64 + (((4 + quad) ^ (d & 7)) << 3));
      acc_o[dj] = mfma16(ap0, bv0, acc_o[dj]);
      acc_o[dj] = mfma16(ap1, bv1, acc_o[dj]);
    }
  }

  // l[q=lq]: sum in-lane parts across the 4 quad groups
  lsum += __shfl_xor(lsum, 16);
  lsum += __shfl_xor(lsum, 32);

  const size_t obase =
      (((size_t)split * BATCH + b) * NHEAD + h) * SLEN + q0 + w * 16;
#pragma unroll
  for (int dj = 0; dj < 4; dj++)
#pragma unroll
    for (int r = 0; r < 4; r++)
      Opart[(obase + quad * 4 + r) * DHEAD + dj * 16 + lq] = f2bf(acc_o[dj][r]);
  if (quad == 0) Lpart[obase + lq] = lsum;
}

// ======= combine split partials: att = (O0+O1)/(l0+l1), lbuf = l0+l1 ========
__global__ __launch_bounds__(256) void combine_k(
    const unsigned short* __restrict__ Opart, const float* __restrict__ Lpart,
    unsigned short* __restrict__ att, float* __restrict__ lbuf) {
  const int gid = blockIdx.x * 256 + threadIdx.x;
  const int row = gid >> 3;
  const int d8 = (gid & 7) * 8;
  const float l0 = Lpart[row];
  const float l1 = Lpart[(size_t)BATCH * NHEAD * SLEN + row];
  const float lt = l0 + l1;
  const float il = (lt > 0.f) ? 1.f / lt : 0.f;
  const bf16x8 o0 = *(const bf16x8*)(Opart + (size_t)row * DHEAD + d8);
  const bf16x8 o1 = *(const bf16x8*)(Opart + (size_t)(BATCH * NHEAD * SLEN) * DHEAD +
                                     (size_t)row * DHEAD + d8);
  const int b = row >> 15, hh = (row >> 11) & 15, q = row & 2047;
  unsigned short* dst = att + (size_t)(b * SLEN + q) * DMODEL + hh * 64 + d8;
  float vv[8];
#pragma unroll
  for (int j = 0; j < 8; j++)
    vv[j] = (bf2f((unsigned short)o0[j]) + bf2f((unsigned short)o1[j])) * il;
  uint4 u;
  u.x = pk_bf16(vv[0], vv[1]);
  u.y = pk_bf16(vv[2], vv[3]);
  u.z = pk_bf16(vv[4], vv[5]);
  u.w = pk_bf16(vv[6], vv[7]);
  *(uint4*)dst = u;
  if ((gid & 7) == 0) lbuf[row] = lt;
}

// ======= attn_avg[b,q,k] = (1/H) sum_h exp(s_h(q,k)) / l[b,h,q]  (m=0) ======
// il (1/l) for all heads precomputed in LDS; mask as per-lane additive bias.
__global__ __launch_bounds__(256) void attn_avg_mfma_k(
    const unsigned short* __restrict__ Qp, const unsigned short* __restrict__ Kp,
    const float* __restrict__ lbuf, const int* __restrict__ mask,
    float* __restrict__ aout) {
  __shared__ unsigned short Ks[64 * 64];  // XOR-swizzled
  __shared__ float ilL[NHEAD * 64];       // 4 KB
  const int t = threadIdx.x;
  const int w = t >> 6, l = t & 63, quad = l >> 4, lq = l & 15;
  const int k0 = blockIdx.x * 64, q0 = blockIdx.y * 64, b = blockIdx.z;

  for (int i = t; i < NHEAD * 64; i += 256) {
    const float lv = lbuf[(b * NHEAD + (i >> 6)) * SLEN + q0 + (i & 63)];
    ilL[i] = (lv > 0.f) ? 1.f / lv : 0.f;
  }
  float bb[4];
#pragma unroll
  for (int ti = 0; ti < 4; ti++)
    bb[ti] = mask[b * SLEN + k0 + ti * 16 + lq] ? 0.f : -INFINITY;

  floatx4 acc[4];
#pragma unroll
  for (int ti = 0; ti < 4; ti++) acc[ti] = (floatx4){0.f, 0.f, 0.f, 0.f};

  int krow[2], kchunk[2];
#pragma unroll
  for (int jj = 0; jj < 2; jj++) {
    krow[jj] = (w * 2 + jj) * 8 + (l >> 3);
    kchunk[jj] = (l & 7) ^ (krow[jj] & 7);
  }
  const unsigned short* Kbase = Kp + (size_t)(b * SLEN + k0) * DMODEL;
  const unsigned short* qbase =
      Qp + (size_t)(b * SLEN + q0 + w * 16 + lq) * DMODEL;

  for (int h = 0; h < NHEAD; h++) {
    __syncthreads();  // also covers ilL visibility on first iter
#pragma unroll
    for (int jj = 0; jj < 2; jj++)
      gll16(Kbase + (size_t)krow[jj] * DMODEL + h * 64 + kchunk[jj] * 8,
            Ks + (w * 2 + jj) * 512);
    __syncthreads();

    const bf16x8 aq0 = *(const bf16x8*)(qbase + h * 64 + quad * 8);
    const bf16x8 aq1 = *(const bf16x8*)(qbase + h * 64 + 32 + quad * 8);
    const float4 il4 = *(const float4*)&ilL[h * 64 + w * 16 + quad * 4];
    const float ila[4] = {il4.x, il4.y, il4.z, il4.w};
#pragma unroll
    for (int ti = 0; ti < 4; ti++) {
      const int kk = ti * 16 + lq;
      const bf16x8 bk0 = *(const bf16x8*)(Ks + kk * 64 + ((quad ^ (kk & 7)) << 3));
      const bf16x8 bk1 =
          *(const bf16x8*)(Ks + kk * 64 + (((4 + quad) ^ (kk & 7)) << 3));
      floatx4 z = (floatx4){0.f, 0.f, 0.f, 0.f};
      z = mfma16(aq0, bk0, z);
      z = mfma16(aq1, bk1, z);
#pragma unroll
      for (int r = 0; r < 4; r++)
        acc[ti][r] = fmaf(__expf(fmaf(z[r], 0.125f, bb[ti])), ila[r], acc[ti][r]);
    }
  }
  const float ih = 1.f / NHEAD;
#pragma unroll
  for (int ti = 0; ti < 4; ti++)
#pragma unroll
    for (int r = 0; r < 4; r++)
      aout[(size_t)(b * SLEN + q0 + w * 16 + quad * 4 + r) * SLEN + k0 +
           ti * 16 + lq] = acc[ti][r] * ih;
}

extern "C" void kernel_launch(void* const* d_in, const int* in_sizes, int n_in,
                              void* d_out, int out_size, void* d_ws, size_t ws_size,
                              hipStream_t stream) {
  const float* q   = (const float*)d_in[0];
  const float* k   = (const float*)d_in[1];
  const float* v   = (const float*)d_in[2];
  const float* Wq  = (const float*)d_in[3];
  const float* bq  = (const float*)d_in[4];
  const float* Wk  = (const float*)d_in[5];
  const float* bk  = (const float*)d_in[6];
  const float* Wv  = (const float*)d_in[7];
  const float* bv  = (const float*)d_in[8];
  const float* Wfc = (const float*)d_in[9];
  const float* bfc = (const float*)d_in[10];
  const int* mask  = (const int*)d_in[11];

  float* out      = (float*)d_out;                 // [B,S,2D] = 33.5 MB
  float* attn_avg = out + (size_t)MROWS * DOUT;    // [B,S,S]  = 33.5 MB

  // d_out `out` region scratch (dead before the FC writes it):
  // phase 1: qb/kb/vb bf16 (33.5 MB); phase 2: Opart bf16 16 MB + Lpart 512 KB.
  unsigned short* qb = (unsigned short*)d_out;
  unsigned short* kb = qb + (1u << 22);
  unsigned short* vb = kb + (1u << 22);
  unsigned short* Opart = (unsigned short*)d_out;
  float* Lpart = (float*)((char*)d_out + (size_t)NSPLIT * BATCH * NHEAD * SLEN * DHEAD * 2);

  // ws (bf16 elems): WqT 1M | WkT 1M | WvT 2M | WfcT 2M | Qp 4M | Kp 4M |
  // VT 4M | att 4M | lbuf f32 64K
  unsigned short* wsb  = (unsigned short*)d_ws;
  unsigned short* WqT  = wsb;
  unsigned short* WkT  = wsb + (1u << 20);
  unsigned short* WvT  = wsb + (2u << 20);
  unsigned short* WfcT = wsb + (4u << 20);
  unsigned short* Qp   = wsb + (6u << 20);
  unsigned short* Kp   = Qp + (1u << 22);
  unsigned short* VT   = Kp + (1u << 22);
  unsigned short* att  = VT + (1u << 22);
  float* lbuf = (float*)(att + (1u << 22));

  // 0) converts + weight transposes (fused launches)
  conv_all_k<<<dim3(8192), dim3(256), 0, stream>>>(q, k, v, qb, kb, vb);
  wtrans_all_k<<<dim3(6144), dim3(256), 0, stream>>>(Wq, Wk, Wv, Wfc,
                                                     WqT, WkT, WvT, WfcT);
  // 1) Q+K+V projections in one launch (1536 blocks)
  proj_k<<<dim3(DMODEL / 64, MROWS / 128, 3), dim3(256), 0, stream>>>(
      qb, kb, vb, WqT, WkT, WvT, bq, bk, bv, Qp, Kp, VT);
  // 2) flash attention (S^T form, k-split x2) -> Opart/Lpart
  flash_mfma_k<<<dim3(SLEN / 64, NHEAD * NSPLIT, BATCH), dim3(256), 0, stream>>>(
      Qp, Kp, VT, mask, Opart, Lpart);
  // 2b) combine -> att (bf16) + lbuf
  combine_k<<<dim3(BATCH * NHEAD * SLEN * DHEAD / 8 / 256), dim3(256), 0, stream>>>(
      Opart, Lpart, att, lbuf);
  // 3) head-averaged attention map
  attn_avg_mfma_k<<<dim3(SLEN / 64, SLEN / 64, BATCH), dim3(256), 0, stream>>>(
      Qp, Kp, lbuf, mask, attn_avg);
  // 4) output FC
  fc_k<<<dim3(DOUT / 64, MROWS / 128), dim3(256), 0, stream>>>(
      att, WfcT, bfc, out);
}